// Round 8
// baseline (2864.323 us; speedup 1.0000x reference)
//
#include <hip/hip_runtime.h>
#include <math.h>

#define DEVFN static __device__ __forceinline__

constexpr int LAYERS = 2;
constexpr int Bz = 4;
constexpr int Cc = 256;
constexpr int Hh = 128;
constexpr int Ww = 128;
constexpr int Dd = 128;
constexpr int NHh = 2;
constexpr int BHt = Bz * NHh;              // 8
constexpr int Mt  = Hh * Ww;               // 16384
constexpr int HK = 16, WK = 16;
constexpr int NSs = HK * WK;               // 256
constexpr int STR = 8, PADc = 4;
constexpr int RPH = 2*Hh - 1, RPW = 2*Ww - 1;  // 255
constexpr float SCALE_F = 0.17677669529663687f; // 32^-0.5

typedef __attribute__((ext_vector_type(8))) short  bf16x8;
typedef __attribute__((ext_vector_type(4))) float  f32x4;

DEVFN float wsum64(float v) {
    #pragma unroll
    for (int off = 32; off > 0; off >>= 1) v += __shfl_xor(v, off, 64);
    return v;
}

// fp32 -> bf16 hi + bf16 lo (RNE both); x ~= hi + lo with ~2^-17 rel error.
DEVFN void split2(float x, ushort& h, ushort& l)
{
    const uint u  = __float_as_uint(x);
    const uint hb = (u + 0x7fffu + ((u >> 16) & 1u)) & 0xffff0000u;
    h = (ushort)(hb >> 16);
    const float r = x - __uint_as_float(hb);
    const uint ul = __float_as_uint(r);
    l = (ushort)((ul + 0x7fffu + ((ul >> 16) & 1u)) >> 16);
}

DEVFN ushort f2bf(float x)
{
    const uint u = __float_as_uint(x);
    return (ushort)((u + 0x7fffu + ((u >> 16) & 1u)) >> 16);
}
DEVFN float bf2f(ushort s) { return __uint_as_float(((uint)s) << 16); }

DEVFN uint shfu(uint v, int src) { return (uint)__shfl((int)v, src, 64); }

DEVFN bf16x8 pack4(uint a, uint b, uint c, uint d)
{
    union { uint u[4]; bf16x8 v; } t;
    t.u[0] = a; t.u[1] = b; t.u[2] = c; t.u[3] = d;
    return t.v;
}

// unpack 8 packed words (hi<<16|lo) into hi/lo bf16x8 fragments
DEVFN void unpack8(uint4 a, uint4 b, bf16x8& h, bf16x8& l)
{
    const uint u[8] = {a.x, a.y, a.z, a.w, b.x, b.y, b.z, b.w};
    #pragma unroll
    for (int j = 0; j < 8; j++) {
        h[j] = (short)(u[j] >> 16);
        l[j] = (short)(u[j] & 0xffffu);
    }
}

// ---------------------------------------------------------------------------
// Generic 1x1-conv projection (fp32 VALU): used only for the small K/V
// projections (Mdim = NSs = 256).
// grid (Mdim/64, Cc/64, Bz), block 256
// ---------------------------------------------------------------------------
__global__ __launch_bounds__(256)
void k_proj(const float* __restrict__ X, const float* __restrict__ W,
            const float* __restrict__ bias, float* __restrict__ Out, int Mdim)
{
    __shared__ float wsm[16][64];
    __shared__ float xsm[16][64];
    const int tid = threadIdx.x;
    const int m0 = blockIdx.x * 64;
    const int o0 = blockIdx.y * 64;
    const float* Xb = X + (size_t)blockIdx.z * Cc * Mdim;
    float* Ob = Out + (size_t)blockIdx.z * Cc * Mdim;
    const int to = tid >> 4;   // 0..15 (o sub /4)
    const int tm = tid & 15;   // 0..15 (m sub /4)
    float acc[4][4] = {{0.f}};
    for (int k0 = 0; k0 < Cc; k0 += 16) {
        {
            const int i = tid >> 2, kq = tid & 3;
            float4 w4 = *(const float4*)(W + (size_t)(o0 + i)*Cc + k0 + kq*4);
            wsm[kq*4+0][i] = w4.x; wsm[kq*4+1][i] = w4.y;
            wsm[kq*4+2][i] = w4.z; wsm[kq*4+3][i] = w4.w;
            const int kk = tid >> 4, jq = tid & 15;
            *(float4*)&xsm[kk][jq*4] =
                *(const float4*)(Xb + (size_t)(k0 + kk)*Mdim + m0 + jq*4);
        }
        __syncthreads();
        #pragma unroll
        for (int kk = 0; kk < 16; kk++) {
            float4 a4 = *(const float4*)&wsm[kk][to*4];
            float4 b4 = *(const float4*)&xsm[kk][tm*4];
            float av[4] = {a4.x, a4.y, a4.z, a4.w};
            float bv[4] = {b4.x, b4.y, b4.z, b4.w};
            #pragma unroll
            for (int ii = 0; ii < 4; ii++)
                #pragma unroll
                for (int jj = 0; jj < 4; jj++)
                    acc[ii][jj] += av[ii] * bv[jj];
        }
        __syncthreads();
    }
    #pragma unroll
    for (int ii = 0; ii < 4; ii++) {
        const int o = o0 + to*4 + ii;
        const float bo = bias[o];
        float4 r4 = make_float4(acc[ii][0]+bo, acc[ii][1]+bo, acc[ii][2]+bo, acc[ii][3]+bo);
        *(float4*)(Ob + (size_t)o*Mdim + m0 + tm*4) = r4;
    }
}

// ---------------------------------------------------------------------------
// MFMA 1x1-conv projection for the big Q GEMM (hi/lo bf16 split):
//   Out[b][o][m] = sum_c Wq[o][c] * X_s[b][c][m] + bias[o]   (one stream s)
// X comes PRE-SPLIT token-major (Xt[bh][m][cc2] packed u32, qsplit layout:
// cc2<128 -> stream A ch (bh&1)*128+cc2 ; cc2>=128 -> stream B).
// A-operand = Wq rows (packed [o][c], k-contiguous) -- same addressing as
// attn's K-fragments.  B-operand = X token columns (k-contiguous).
// Output transposed through LDS (stride 68 -> 2-way banks, free) and stored
// [o][m] coalesced (256B rows).
// grid (Mt/64, Bz), block 256
// ---------------------------------------------------------------------------
__global__ __launch_bounds__(256)
void k_projq_mfma(const uint* __restrict__ Xt, const uint* __restrict__ Wqp,
                  const float* __restrict__ bias, float* __restrict__ Out,
                  int s)
{
    __shared__ __align__(16) float ot[256 * 68];   // 69632 B
    const int tid = threadIdx.x;
    const int m0 = blockIdx.x * 64;
    const int b  = blockIdx.y;
    const int w = tid >> 6, l = tid & 63;
    const int l15 = l & 15, g = l >> 4;
    const int m = m0 + w*16 + l15;

    // ---- B fragments: X token column m, channels c = cs*32 + g*8 + j
    bf16x8 xh[8], xl[8];
    {
        const uint* xp0 = Xt + ((size_t)(b*2 + 0)*Mt + m)*256 + s*128 + g*8;
        const uint* xp1 = Xt + ((size_t)(b*2 + 1)*Mt + m)*256 + s*128 + g*8;
        #pragma unroll
        for (int cs = 0; cs < 8; cs++) {
            const uint* xp = ((cs < 4) ? xp0 : xp1) + (cs & 3)*32;
            const uint4 x0 = *(const uint4*)(xp);
            const uint4 x1 = *(const uint4*)(xp + 4);
            unpack8(x0, x1, xh[cs], xl[cs]);
        }
    }

    // ---- MFMA: acc[nt] holds Out[o = nt*16 + g*4 + r][m]
    f32x4 acc[16];
    #pragma unroll
    for (int nt = 0; nt < 16; nt++) acc[nt] = (f32x4){0.f, 0.f, 0.f, 0.f};

    const uint* wp = Wqp + l15*256 + g*8;
    #pragma unroll
    for (int cs = 0; cs < 8; cs++) {
        #pragma unroll
        for (int nt = 0; nt < 16; nt++) {
            const uint* wpp = wp + nt*4096 + cs*32;
            const uint4 w0 = *(const uint4*)(wpp);
            const uint4 w1 = *(const uint4*)(wpp + 4);
            bf16x8 wh, wl; unpack8(w0, w1, wh, wl);
            acc[nt] = __builtin_amdgcn_mfma_f32_16x16x32_bf16(wh, xh[cs], acc[nt], 0, 0, 0);
            acc[nt] = __builtin_amdgcn_mfma_f32_16x16x32_bf16(wh, xl[cs], acc[nt], 0, 0, 0);
            acc[nt] = __builtin_amdgcn_mfma_f32_16x16x32_bf16(wl, xh[cs], acc[nt], 0, 0, 0);
        }
    }

    // ---- epilogue: bias, LDS transpose, coalesced [o][m] stores
    #pragma unroll
    for (int nt = 0; nt < 16; nt++) {
        #pragma unroll
        for (int r = 0; r < 4; r++) {
            const int o = nt*16 + g*4 + r;
            ot[o*68 + w*16 + l15] = acc[nt][r] + bias[o];
        }
    }
    __syncthreads();
    #pragma unroll
    for (int it = 0; it < 16; it++) {
        const int idx = it*256 + tid;      // 0..4095 float4s
        const int o = idx >> 4, mq = idx & 15;
        const float4 v = *(const float4*)&ot[o*68 + mq*4];
        *(float4*)(Out + ((size_t)b*Cc + o)*Mt + m0 + mq*4) = v;
    }
}

// ---------------------------------------------------------------------------
// Depthwise 9x9 stride-8 pad-4 conv: Y[b,c,i,j], grid (Cc, Bz), block 256
// ---------------------------------------------------------------------------
__global__ __launch_bounds__(256)
void k_dwconv(const float* __restrict__ Q, const float* __restrict__ Wdw,
              const float* __restrict__ Bdw, float* __restrict__ Y)
{
    const int c = blockIdx.x, b = blockIdx.y;
    __shared__ float wsmem[81];
    const int tid = threadIdx.x;
    if (tid < 81) wsmem[tid] = Wdw[c*81 + tid];
    __syncthreads();
    const int i = tid >> 4, j = tid & 15;
    const float* Qc = Q + ((size_t)b*Cc + c)*Mt;
    float acc = Bdw[c];
    const int ybase = i*STR - PADc, xbase = j*STR - PADc;
    #pragma unroll
    for (int u = 0; u < 9; u++) {
        const int y = ybase + u;
        if (y < 0 || y >= Hh) continue;
        #pragma unroll
        for (int v = 0; v < 9; v++) {
            const int x = xbase + v;
            if (x < 0 || x >= Ww) continue;
            acc += wsmem[u*9+v] * Qc[y*Ww + x];
        }
    }
    Y[((size_t)b*Cc + c)*NSs + i*WK + j] = acc;
}

// ---------------------------------------------------------------------------
// Channel-LN + exact GELU + pointwise(2) + ref grid -> Pos[b,s,2]
// grid (NSs, Bz), block 256 (tid = channel)
// ---------------------------------------------------------------------------
DEVFN float block_reduce(float v, float* red, int tid)
{
    red[tid] = v; __syncthreads();
    #pragma unroll
    for (int s2 = 128; s2 > 0; s2 >>= 1) {
        if (tid < s2) red[tid] += red[tid + s2];
        __syncthreads();
    }
    const float r = red[0];
    __syncthreads();
    return r;
}

__global__ __launch_bounds__(256)
void k_lnpw(const float* __restrict__ Y, const float* __restrict__ G,
            const float* __restrict__ Bt, const float* __restrict__ PW,
            float* __restrict__ Pos)
{
    __shared__ float red[256];
    const int ij = blockIdx.x, b = blockIdx.y;
    const int tid = threadIdx.x;
    const float y = Y[((size_t)b*Cc + tid)*NSs + ij];
    const float m = block_reduce(y, red, tid) * (1.f/256.f);
    const float d = y - m;
    const float v = block_reduce(d*d, red, tid) * (1.f/256.f);
    const float g = d * rsqrtf(v + 1e-5f) * G[tid] + Bt[tid];
    const float ge = 0.5f * g * (1.f + erff(g * 0.70710678118654752f));
    const float off0 = block_reduce(ge * PW[tid], red, tid);
    const float off1 = block_reduce(ge * PW[Cc + tid], red, tid);
    if (tid == 0) {
        const int i = ij >> 4, j = ij & 15;
        const float refy = ((float)i + 0.5f) * (2.f/15.f) - 1.f;
        const float refx = ((float)j + 0.5f) * (2.f/15.f) - 1.f;
        Pos[((size_t)b*NSs + ij)*2 + 0] = off0 + refy;
        Pos[((size_t)b*NSs + ij)*2 + 1] = off1 + refx;
    }
}

// ---------------------------------------------------------------------------
// Bilinear grid sample (zero padding): Xs[b,c,s] = bilerp(X[b,c], Pos[b,s])
// grid (Cc, Bz), block 256 (tid = sample index s)
// ---------------------------------------------------------------------------
__global__ __launch_bounds__(256)
void k_gsample(const float* __restrict__ X, const float* __restrict__ Pos,
               float* __restrict__ Xs)
{
    const int c = blockIdx.x, b = blockIdx.y, s = threadIdx.x;
    const float py = Pos[((size_t)b*NSs + s)*2 + 0];
    const float px = Pos[((size_t)b*NSs + s)*2 + 1];
    const float x = (px + 1.f) * 0.5f * (float)(Ww - 1);
    const float y = (py + 1.f) * 0.5f * (float)(Hh - 1);
    const float x0 = floorf(x), y0 = floorf(y);
    const float wx1 = x - x0, wx0 = 1.f - wx1;
    const float wy1 = y - y0, wy0 = 1.f - wy1;
    const float* Xc = X + ((size_t)b*Cc + c)*Mt;
    float acc = 0.f;
    #pragma unroll
    for (int t = 0; t < 4; t++) {
        const float xx = x0 + (float)(t & 1);
        const float yy = y0 + (float)(t >> 1);
        float w = ((t & 1) ? wx1 : wx0) * ((t >> 1) ? wy1 : wy0);
        const bool valid = (xx >= 0.f) && (xx <= (float)(Ww-1)) &&
                           (yy >= 0.f) && (yy <= (float)(Hh-1));
        const int xi = (int)fminf(fmaxf(xx, 0.f), (float)(Ww-1));
        const int yi = (int)fminf(fmaxf(yy, 0.f), (float)(Hh-1));
        acc += (valid ? w : 0.f) * Xc[yi*Ww + xi];
    }
    Xs[((size_t)b*Cc + c)*NSs + s] = acc;
}

// ---------------------------------------------------------------------------
// Split+transpose pre-pass: pair of fp32 [b][c][m] -> packed u32 (hi<<16|lo)
// Out[bh][m][cc2], cc2 = stream-a ch 0..127, stream-b ch 128..255.
// Used for both the layer input (Xt) and the computed Q (Qs).
// grid (Mt/64, BHt), block 256
// ---------------------------------------------------------------------------
__global__ __launch_bounds__(256)
void k_qsplit(const float* __restrict__ Qa, const float* __restrict__ Qb,
              uint* __restrict__ Qs)
{
    __shared__ float tile[64][65];
    const int tid = threadIdx.x;
    const int m0 = blockIdx.x * 64;
    const int bh = blockIdx.y;
    const int b = bh >> 1, h = bh & 1;
    for (int ccblk = 0; ccblk < 4; ccblk++) {
        #pragma unroll
        for (int i = 0; i < 4; i++) {
            const int idx = i*256 + tid;           // 0..1023
            const int ccl = idx >> 4, mq = idx & 15;
            const int cc2 = ccblk*64 + ccl;
            const float* src = (cc2 >> 7) ? Qb : Qa;
            *(float4*)&tile[ccl][mq*4] =
                *(const float4*)(src + ((size_t)b*Cc + h*Dd + (cc2 & 127))*Mt + m0 + mq*4);
        }
        __syncthreads();
        #pragma unroll
        for (int i = 0; i < 16; i++) {
            const int idx = i*256 + tid;
            const int ml = idx >> 6, ccl = idx & 63;
            ushort hi, lo; split2(tile[ccl][ml], hi, lo);
            Qs[((size_t)bh*Mt + m0 + ml)*256 + ccblk*64 + ccl] = ((uint)hi << 16) | lo;
        }
        __syncthreads();
    }
}

// ---------------------------------------------------------------------------
// K split+transpose pre-pass: K fp32 [b][c][n] -> packed u32 Ktp[bh][n][cc2]
// grid (NSs/64, BHt), block 256
// ---------------------------------------------------------------------------
__global__ __launch_bounds__(256)
void k_ksplit(const float* __restrict__ Ka, const float* __restrict__ Kb,
              uint* __restrict__ Ktp)
{
    __shared__ float tile[64][65];
    const int tid = threadIdx.x;
    const int n0 = blockIdx.x * 64;
    const int bh = blockIdx.y;
    const int b = bh >> 1, h = bh & 1;
    for (int ccblk = 0; ccblk < 4; ccblk++) {
        #pragma unroll
        for (int i = 0; i < 16; i++) {
            const int idx = i*256 + tid;
            const int ccl = idx >> 6, nl = idx & 63;
            const int cc2 = ccblk*64 + ccl;
            const float* src = (cc2 >> 7) ? Kb : Ka;
            tile[ccl][nl] = src[((size_t)b*Cc + h*Dd + (cc2 & 127))*NSs + n0 + nl];
        }
        __syncthreads();
        #pragma unroll
        for (int i = 0; i < 16; i++) {
            const int idx = i*256 + tid;
            const int nl = idx >> 6, ccl = idx & 63;
            ushort hi, lo; split2(tile[ccl][nl], hi, lo);
            Ktp[((size_t)bh*NSs + n0 + nl)*256 + ccblk*64 + ccl] = ((uint)hi << 16) | lo;
        }
        __syncthreads();
    }
}

// ---------------------------------------------------------------------------
// V split pre-pass: V fp32 [b][c][n] -> packed u32 Vsp[bh][j][n]
// grid (2048), block 256
// ---------------------------------------------------------------------------
__global__ __launch_bounds__(256)
void k_vsplit(const float* __restrict__ Va, const float* __restrict__ Vb,
              uint* __restrict__ Vsp)
{
    const size_t e = (size_t)blockIdx.x*256 + threadIdx.x;
    const int n  = (int)(e & 255);
    const int j  = (int)((e >> 8) & 255);
    const int bh = (int)(e >> 16);
    const int b = bh >> 1, h = bh & 1;
    const float* src = (j >> 7) ? Vb : Va;
    const float v = src[((size_t)b*Cc + h*Dd + (j & 127))*NSs + n];
    ushort hi, lo; split2(v, hi, lo);
    Vsp[e] = ((uint)hi << 16) | lo;
}

// ---------------------------------------------------------------------------
// FFN weight pack pre-pass: 4 matrices (128x128, row-major [o][k]) -> packed
// u32 (hi<<16|lo).  grid (64, 4), block 256.
// ---------------------------------------------------------------------------
__global__ __launch_bounds__(256)
void k_wsplit4(const float* __restrict__ W0, const float* __restrict__ W1,
               const float* __restrict__ W2, const float* __restrict__ W3,
               uint* __restrict__ Wp)
{
    const int mat = blockIdx.y;
    const float* W = (mat == 0) ? W0 : (mat == 1) ? W1 : (mat == 2) ? W2 : W3;
    const int i = blockIdx.x*256 + threadIdx.x;   // 0..16383
    ushort hi, lo; split2(W[i], hi, lo);
    Wp[(size_t)mat*Dd*Dd + i] = ((uint)hi << 16) | lo;
}

// ---------------------------------------------------------------------------
// Single 256x256 weight pack (wq): grid (256), block 256.
// ---------------------------------------------------------------------------
__global__ __launch_bounds__(256)
void k_wsplit1(const float* __restrict__ W, uint* __restrict__ Wp)
{
    const int i = blockIdx.x*256 + threadIdx.x;   // 0..65535
    ushort hi, lo; split2(W[i], hi, lo);
    Wp[i] = ((uint)hi << 16) | lo;
}

// ---------------------------------------------------------------------------
// MFMA attention v4 (validated round 7; unchanged this round).
// grid (Mt/64, BHt), block 256
// ---------------------------------------------------------------------------
__global__ __launch_bounds__(256, 2)
void k_attn_mfma(const uint* __restrict__ Qs, const uint* __restrict__ Ktp,
                 const uint* __restrict__ Vsp,
                 const float* __restrict__ Pos, const float* __restrict__ Rpe,
                 float* __restrict__ Oa, float* __restrict__ Ob)
{
    constexpr int GS = 66;                 // 65 entries + 1 pad
    __shared__ ushort Gt[NSs * GS];        // 33792 B (bf16)
    __shared__ float fxs[NSs];             // 1024 B
    __shared__ __align__(16) uint kvbuf[2][4096];   // 2 x 16KB staging dbuf
    const int tid = threadIdx.x;
    const int m0 = blockIdx.x * 64;
    const int bh = blockIdx.y;
    const int b = bh >> 1, h = bh & 1;
    const int j0 = m0 & 127;               // jq base for this block
    const int iq = m0 >> 7;                // constant over the block
    const float* Rh = Rpe + (size_t)h * RPH * RPW;

    // ---- G-table build: thread n handles sample n (contiguous row reads)
    {
        const int n = tid;
        const float py = Pos[((size_t)b*NSs + n)*2 + 0];
        const float px = Pos[((size_t)b*NSs + n)*2 + 1];
        const float xf = (float)j0 + 63.5f - 63.5f*px;   // x(m) = xf + dm
        const float yf = (float)iq + 63.5f - 63.5f*py;   // y const over block
        const float xbf = floorf(xf), ybf = floorf(yf);
        const float fx = xf - xbf, fy = yf - ybf;
        fxs[n] = fx;
        const int yb = (int)ybf;
        const float wy0 = (1.f - fy) * ((yb   >= 0 && yb   <= RPH-1) ? 1.f : 0.f);
        const float wy1 = fy         * ((yb+1 >= 0 && yb+1 <= RPH-1) ? 1.f : 0.f);
        const int y0c = yb   < 0 ? 0 : (yb   > RPH-1 ? RPH-1 : yb);
        const int y1c = yb+1 < 0 ? 0 : (yb+1 > RPH-1 ? RPH-1 : yb+1);
        const float* r0 = Rh + (size_t)y0c * RPW;
        const float* r1 = Rh + (size_t)y1c * RPW;
        const int xb = (int)xbf;
        #pragma unroll 4
        for (int t = 0; t <= 64; t++) {
            const int xi = xb + t;
            const int xc = xi < 0 ? 0 : (xi > RPW-1 ? RPW-1 : xi);
            const float v = wy0*r0[xc] + wy1*r1[xc];
            Gt[n*GS + t] = f2bf((xi >= 0 && xi <= RPW-1) ? v : 0.f);
        }
    }

    const int w = tid >> 6, l = tid & 63;
    const int l15 = l & 15, g = l >> 4;
    const int mcol = m0 + w*16 + l15;      // this lane's output column m

    // staging: copy one 16KB chunk (16 rows x 1KB) into kvbuf[p], swizzled.
    const uint* kbase = Ktp + (size_t)bh * 65536;
    const uint* vbase = Vsp + (size_t)bh * 65536;
    char* const kv0 = (char*)&kvbuf[0][0];
    char* const kv1 = (char*)&kvbuf[1][0];
    auto stage = [&](int p, const uint* chunk) {
        char* dst = p ? kv1 : kv0;
        #pragma unroll
        for (int r = 0; r < 4; r++) {
            const int idx = r*1024 + tid*4;              // u32 index in chunk
            const uint4 v = *(const uint4*)(chunk + idx);
            const int byte = idx << 2;
            const int swz = ((byte >> 10) & 7) << 4;
            *(uint4*)(dst + (byte ^ swz)) = v;
        }
    };

    // ---- Q fragments -> registers, unpacked once (64 VGPR)
    bf16x8 qh[8], ql[8];
    {
        const uint* qp = Qs + ((size_t)bh*Mt + mcol)*256 + g*8;
        #pragma unroll
        for (int cs = 0; cs < 8; cs++) {
            const uint4 q0 = *(const uint4*)(qp + cs*32);
            const uint4 q1 = *(const uint4*)(qp + cs*32 + 4);
            unpack8(q0, q1, qh[cs], ql[cs]);
        }
    }

    // ---- QK^T with staged K: acc[nt] = S[n = nt*16+g*4+r][m = mcol]
    f32x4 acc[16];
    #pragma unroll
    for (int nt = 0; nt < 16; nt++) acc[nt] = (f32x4){0.f, 0.f, 0.f, 0.f};

    const int rowb = l15 << 10;
    const int sw = (l15 & 7) << 4;

    stage(0, kbase);
    __syncthreads();                       // chunk 0 ready (+ Gt/fxs ready)
    #pragma unroll
    for (int nt = 0; nt < 16; nt++) {
        if (nt < 15) stage((nt + 1) & 1, kbase + (nt + 1)*4096);
        const char* bufc = (nt & 1) ? kv1 : kv0;
        #pragma unroll
        for (int cs = 0; cs < 8; cs++) {
            const int a0 = rowb + cs*128 + g*32;
            const uint4 k0 = *(const uint4*)(bufc + (a0 ^ sw));
            const uint4 k1 = *(const uint4*)(bufc + ((a0 + 16) ^ sw));
            bf16x8 kh, kl; unpack8(k0, k1, kh, kl);
            acc[nt] = __builtin_amdgcn_mfma_f32_16x16x32_bf16(kh, qh[cs], acc[nt], 0, 0, 0);
            acc[nt] = __builtin_amdgcn_mfma_f32_16x16x32_bf16(kh, ql[cs], acc[nt], 0, 0, 0);
            acc[nt] = __builtin_amdgcn_mfma_f32_16x16x32_bf16(kl, qh[cs], acc[nt], 0, 0, 0);
        }
        __syncthreads();                   // next chunk landed; buf free
    }

    // ---- bias + softmax (row m is wave-local across the 4 g-lanes)
    const int dm = w*16 + l15;
    float mx = -1e30f;
    #pragma unroll
    for (int nt = 0; nt < 16; nt++) {
        #pragma unroll
        for (int r = 0; r < 4; r++) {
            const int n = nt*16 + g*4 + r;
            const float g0 = bf2f(Gt[n*GS + dm]);
            const float g1 = bf2f(Gt[n*GS + dm + 1]);
            const float bias = g0 + fxs[n]*(g1 - g0);
            const float s = SCALE_F*acc[nt][r] + bias;
            acc[nt][r] = s;
            mx = fmaxf(mx, s);
        }
    }
    mx = fmaxf(mx, __shfl_xor(mx, 16, 64));
    mx = fmaxf(mx, __shfl_xor(mx, 32, 64));
    float sum = 0.f;
    #pragma unroll
    for (int nt = 0; nt < 16; nt++)
        #pragma unroll
        for (int r = 0; r < 4; r++) {
            const float e = __expf(acc[nt][r] - mx);
            acc[nt][r] = e;
            sum += e;
        }
    sum += __shfl_xor(sum, 16, 64);
    sum += __shfl_xor(sum, 32, 64);
    const float inv = 1.f / sum;

    // ---- pack P to bf16 hi/lo word pairs (per nt: words [r0|r1], [r2|r3])
    uint hU0[16], hU1[16], lU0[16], lU1[16];
    #pragma unroll
    for (int nt = 0; nt < 16; nt++) {
        ushort ph_[4], pl_[4];
        #pragma unroll
        for (int r = 0; r < 4; r++) split2(acc[nt][r] * inv, ph_[r], pl_[r]);
        hU0[nt] = (uint)ph_[0] | ((uint)ph_[1] << 16);
        hU1[nt] = (uint)ph_[2] | ((uint)ph_[3] << 16);
        lU0[nt] = (uint)pl_[0] | ((uint)pl_[1] << 16);
        lU1[nt] = (uint)pl_[2] | ((uint)pl_[3] << 16);
    }

    // ---- shuffle-precompute PV A-fragments (identical across jt)
    const int srcA = (((2*g)     & 3) << 4) | l15;
    const int srcB = (((2*g + 1) & 3) << 4) | l15;
    const bool hi2 = (g >> 1) & 1;
    bf16x8 ph[8], pl[8];
    #pragma unroll
    for (int cs = 0; cs < 8; cs++) {
        uint A00 = shfu(hU0[2*cs], srcA), A01 = shfu(hU0[2*cs+1], srcA);
        uint A10 = shfu(hU1[2*cs], srcA), A11 = shfu(hU1[2*cs+1], srcA);
        uint B00 = shfu(hU0[2*cs], srcB), B01 = shfu(hU0[2*cs+1], srcB);
        uint B10 = shfu(hU1[2*cs], srcB), B11 = shfu(hU1[2*cs+1], srcB);
        ph[cs] = pack4(hi2 ? A01 : A00, hi2 ? A11 : A10,
                       hi2 ? B01 : B00, hi2 ? B11 : B10);
        A00 = shfu(lU0[2*cs], srcA); A01 = shfu(lU0[2*cs+1], srcA);
        A10 = shfu(lU1[2*cs], srcA); A11 = shfu(lU1[2*cs+1], srcA);
        B00 = shfu(lU0[2*cs], srcB); B01 = shfu(lU0[2*cs+1], srcB);
        B10 = shfu(lU1[2*cs], srcB); B11 = shfu(lU1[2*cs+1], srcB);
        pl[cs] = pack4(hi2 ? A01 : A00, hi2 ? A11 : A10,
                       hi2 ? B01 : B00, hi2 ? B11 : B10);
    }

    // ---- PV with staged V, jt-outer (per-jt f32x4 accumulator)
    const size_t rowbase = ((size_t)bh*Mt + mcol)*Dd;
    stage(0, vbase);                       // kvbuf[0] free: QK done (barrier)
    __syncthreads();
    for (int jt = 0; jt < 16; jt++) {
        if (jt < 15) stage((jt + 1) & 1, vbase + (jt + 1)*4096);
        const char* bufc = (jt & 1) ? kv1 : kv0;
        f32x4 a2 = (f32x4){0.f, 0.f, 0.f, 0.f};
        #pragma unroll
        for (int cs = 0; cs < 8; cs++) {
            const int a0 = rowb + cs*128 + g*32;
            const uint4 v0 = *(const uint4*)(bufc + (a0 ^ sw));
            const uint4 v1 = *(const uint4*)(bufc + ((a0 + 16) ^ sw));
            bf16x8 vh, vl; unpack8(v0, v1, vh, vl);
            a2 = __builtin_amdgcn_mfma_f32_16x16x32_bf16(vh, ph[cs], a2, 0, 0, 0);
            a2 = __builtin_amdgcn_mfma_f32_16x16x32_bf16(vh, pl[cs], a2, 0, 0, 0);
            a2 = __builtin_amdgcn_mfma_f32_16x16x32_bf16(vl, ph[cs], a2, 0, 0, 0);
        }
        const float4 o = make_float4(a2[0], a2[1], a2[2], a2[3]);
        const int jv0 = jt*16 + g*4;
        if (jt < 8) *(float4*)(Oa + rowbase + jv0) = o;
        else        *(float4*)(Ob + rowbase + jv0 - 128) = o;
        __syncthreads();
    }
}

// ---------------------------------------------------------------------------
// Complex whitening LN (attention branch) + residual from (B,C,M) input.
// grid (Mt/32, BHt), block 256. X2 written token-major.
// ---------------------------------------------------------------------------
__global__ __launch_bounds__(256)
void k_cln_attn(const float* __restrict__ Oa, const float* __restrict__ Ob,
                const float* __restrict__ Xa, const float* __restrict__ Xb,
                const float* __restrict__ Pgrr, const float* __restrict__ Pgri,
                const float* __restrict__ Pgii, const float* __restrict__ Pbr,
                const float* __restrict__ Pbi,
                float* __restrict__ X2a, float* __restrict__ X2b)
{
    __shared__ float ra[32][132];
    __shared__ float rb[32][132];
    const int tid = threadIdx.x;
    const int m0 = blockIdx.x * 32;
    const int bh = blockIdx.y;
    const int b = bh >> 1, h = bh & 1;
    {
        const float* Xpa = Xa + ((size_t)b*Cc + h*Dd)*Mt + m0;
        const float* Xpb = Xb + ((size_t)b*Cc + h*Dd)*Mt + m0;
        for (int idx = tid; idx < 1024; idx += 256) {
            const int c = idx >> 3, jq = idx & 7;
            float4 a4 = *(const float4*)(Xpa + (size_t)c*Mt + jq*4);
            float4 b4 = *(const float4*)(Xpb + (size_t)c*Mt + jq*4);
            ra[jq*4+0][c] = a4.x; ra[jq*4+1][c] = a4.y;
            ra[jq*4+2][c] = a4.z; ra[jq*4+3][c] = a4.w;
            rb[jq*4+0][c] = b4.x; rb[jq*4+1][c] = b4.y;
            rb[jq*4+2][c] = b4.z; rb[jq*4+3][c] = b4.w;
        }
    }
    __syncthreads();
    const int wave = tid >> 6, lane = tid & 63;
    const float grr0 = Pgrr[lane], grr1 = Pgrr[lane+64];
    const float gri0 = Pgri[lane], gri1 = Pgri[lane+64];
    const float gii0 = Pgii[lane], gii1 = Pgii[lane+64];
    const float br0  = Pbr[lane],  br1  = Pbr[lane+64];
    const float bi0  = Pbi[lane],  bi1  = Pbi[lane+64];
    for (int r = wave; r < 32; r += 4) {
        const size_t rowoff = ((size_t)bh*Mt + m0 + r)*Dd;
        float a0 = Oa[rowoff + lane], a1 = Oa[rowoff + lane + 64];
        float c0 = Ob[rowoff + lane], c1 = Ob[rowoff + lane + 64];
        const float ma = wsum64(a0 + a1) * (1.f/128.f);
        const float mb = wsum64(c0 + c1) * (1.f/128.f);
        a0 -= ma; a1 -= ma; c0 -= mb; c1 -= mb;
        const float vrr = wsum64(a0*a0 + a1*a1) * (1.f/128.f) + 1e-20f;
        const float vii = wsum64(c0*c0 + c1*c1) * (1.f/128.f) + 1e-20f;
        const float vri = wsum64(a0*c0 + a1*c1) * (1.f/128.f);
        const float s = sqrtf(fmaxf(vrr*vii - vri*vri, 0.f));
        const float t = sqrtf(vrr + vii + 2.f*s);
        const float inv = 1.f / (s*t);
        const float wrr = (vii + s)*inv, wii = (vrr + s)*inv, wri = -vri*inv;
        const float na0 = wrr*a0 + wri*c0, nb0 = wri*a0 + wii*c0;
        const float na1 = wrr*a1 + wri*c1, nb1 = wri*a1 + wii*c1;
        X2a[rowoff + lane]      = ra[r][lane]    + grr0*na0 + gri0*nb0 + br0;
        X2a[rowoff + lane + 64] = ra[r][lane+64] + grr1*na1 + gri1*nb1 + br1;
        X2b[rowoff + lane]      = rb[r][lane]    + gri0*na0 + gii0*nb0 + bi0;
        X2b[rowoff + lane + 64] = rb[r][lane+64] + gri1*na1 + gii1*nb1 + bi1;
    }
}

// ---------------------------------------------------------------------------
// MFMA complex linear (hi/lo bf16 split emulation of fp32):
//   Ha = A@Wr^T - B@Wi^T + br ; Hb = A@Wi^T + B@Wr^T + bi ; optional relu.
// grid (BHt*Mt/64), block 256
// ---------------------------------------------------------------------------
__global__ __launch_bounds__(256)
void k_ffn_mfma(const float* __restrict__ A, const float* __restrict__ Bm,
                const uint* __restrict__ Wrp, const uint* __restrict__ Wip,
                const float* __restrict__ br, const float* __restrict__ bi,
                float* __restrict__ Ha, float* __restrict__ Hb, int relu)
{
    const int tid = threadIdx.x;
    const size_t r0 = (size_t)blockIdx.x * 64;
    const int w = tid >> 6, l = tid & 63;
    const int l15 = l & 15, g = l >> 4;
    const size_t row = r0 + (size_t)w*16 + l15;

    f32x4 accr[8], acci[8];
    #pragma unroll
    for (int nt = 0; nt < 8; nt++) {
        accr[nt] = (f32x4){0.f, 0.f, 0.f, 0.f};
        acci[nt] = (f32x4){0.f, 0.f, 0.f, 0.f};
    }

    const float* ap = A  + row*Dd + g*8;
    const float* bp = Bm + row*Dd + g*8;
    const uint*  wr = Wrp + l15*Dd + g*8;   // + nt*2048 + cs*32
    const uint*  wi = Wip + l15*Dd + g*8;

    #pragma unroll
    for (int cs = 0; cs < 4; cs++) {
        const float4 a0 = *(const float4*)(ap + cs*32);
        const float4 a1 = *(const float4*)(ap + cs*32 + 4);
        const float4 b0 = *(const float4*)(bp + cs*32);
        const float4 b1 = *(const float4*)(bp + cs*32 + 4);
        const float av[8] = {a0.x,a0.y,a0.z,a0.w,a1.x,a1.y,a1.z,a1.w};
        const float bv[8] = {b0.x,b0.y,b0.z,b0.w,b1.x,b1.y,b1.z,b1.w};
        bf16x8 ah, al, bh_, bl_, nh, nl;
        #pragma unroll
        for (int j = 0; j < 8; j++) {
            ushort h1, l1; split2(av[j], h1, l1);
            ah[j] = (short)h1; al[j] = (short)l1;
            split2(bv[j], h1, l1);
            bh_[j] = (short)h1; bl_[j] = (short)l1;
            nh[j] = (short)(h1 ^ 0x8000);
            nl[j] = (short)(l1 ^ 0x8000);
        }
        #pragma unroll
        for (int nt = 0; nt < 8; nt++) {
            const uint* wrp2 = wr + nt*2048 + cs*32;
            const uint* wip2 = wi + nt*2048 + cs*32;
            const uint4 r0v = *(const uint4*)(wrp2);
            const uint4 r1v = *(const uint4*)(wrp2 + 4);
            const uint4 i0v = *(const uint4*)(wip2);
            const uint4 i1v = *(const uint4*)(wip2 + 4);
            bf16x8 wrh, wrl, wih, wil;
            unpack8(r0v, r1v, wrh, wrl);
            unpack8(i0v, i1v, wih, wil);
            accr[nt] = __builtin_amdgcn_mfma_f32_16x16x32_bf16(wrh, ah, accr[nt], 0, 0, 0);
            accr[nt] = __builtin_amdgcn_mfma_f32_16x16x32_bf16(wrh, al, accr[nt], 0, 0, 0);
            accr[nt] = __builtin_amdgcn_mfma_f32_16x16x32_bf16(wrl, ah, accr[nt], 0, 0, 0);
            accr[nt] = __builtin_amdgcn_mfma_f32_16x16x32_bf16(wih, nh, accr[nt], 0, 0, 0);
            accr[nt] = __builtin_amdgcn_mfma_f32_16x16x32_bf16(wih, nl, accr[nt], 0, 0, 0);
            accr[nt] = __builtin_amdgcn_mfma_f32_16x16x32_bf16(wil, nh, accr[nt], 0, 0, 0);
            acci[nt] = __builtin_amdgcn_mfma_f32_16x16x32_bf16(wih, ah, acci[nt], 0, 0, 0);
            acci[nt] = __builtin_amdgcn_mfma_f32_16x16x32_bf16(wih, al, acci[nt], 0, 0, 0);
            acci[nt] = __builtin_amdgcn_mfma_f32_16x16x32_bf16(wil, ah, acci[nt], 0, 0, 0);
            acci[nt] = __builtin_amdgcn_mfma_f32_16x16x32_bf16(wrh, bh_, acci[nt], 0, 0, 0);
            acci[nt] = __builtin_amdgcn_mfma_f32_16x16x32_bf16(wrh, bl_, acci[nt], 0, 0, 0);
            acci[nt] = __builtin_amdgcn_mfma_f32_16x16x32_bf16(wrl, bh_, acci[nt], 0, 0, 0);
        }
    }

    #pragma unroll
    for (int nt = 0; nt < 8; nt++) {
        const int n0 = nt*16 + g*4;
        const float4 vbr = *(const float4*)(br + n0);
        const float4 vbi = *(const float4*)(bi + n0);
        const float brv[4] = {vbr.x, vbr.y, vbr.z, vbr.w};
        const float biv[4] = {vbi.x, vbi.y, vbi.z, vbi.w};
        float4 orv, oiv;
        float* po = &orv.x; float* pj = &oiv.x;
        #pragma unroll
        for (int r = 0; r < 4; r++) {
            float hr = accr[nt][r] + brv[r];
            float hi = acci[nt][r] + biv[r];
            if (relu) { hr = fmaxf(hr, 0.f); hi = fmaxf(hi, 0.f); }
            po[r] = hr; pj[r] = hi;
        }
        *(float4*)(Ha + row*Dd + n0) = orv;
        *(float4*)(Hb + row*Dd + n0) = oiv;
    }
}

// ---------------------------------------------------------------------------
// Complex whitening LN (FFN branch) + residual (token-major) + transpose out
// to (B,C,M). grid (Mt/32, BHt), block 256
// ---------------------------------------------------------------------------
__global__ __launch_bounds__(256)
void k_cln_ffn(const float* __restrict__ Ha2, const float* __restrict__ Hb2,
               const float* __restrict__ X2a, const float* __restrict__ X2b,
               const float* __restrict__ Pgrr, const float* __restrict__ Pgri,
               const float* __restrict__ Pgii, const float* __restrict__ Pbr,
               const float* __restrict__ Pbi,
               float* __restrict__ OutA, float* __restrict__ OutB)
{
    __shared__ float oA[128][36];
    __shared__ float oB[128][36];
    const int tid = threadIdx.x;
    const int m0 = blockIdx.x * 32;
    const int bh = blockIdx.y;
    const int b = bh >> 1, h = bh & 1;
    const int wave = tid >> 6, lane = tid & 63;
    const float grr0 = Pgrr[lane], grr1 = Pgrr[lane+64];
    const float gri0 = Pgri[lane], gri1 = Pgri[lane+64];
    const float gii0 = Pgii[lane], gii1 = Pgii[lane+64];
    const float br0  = Pbr[lane],  br1  = Pbr[lane+64];
    const float bi0  = Pbi[lane],  bi1  = Pbi[lane+64];
    for (int r = wave; r < 32; r += 4) {
        const size_t rowoff = ((size_t)bh*Mt + m0 + r)*Dd;
        float a0 = Ha2[rowoff + lane], a1 = Ha2[rowoff + lane + 64];
        float c0 = Hb2[rowoff + lane], c1 = Hb2[rowoff + lane + 64];
        const float ma = wsum64(a0 + a1) * (1.f/128.f);
        const float mb = wsum64(c0 + c1) * (1.f/128.f);
        a0 -= ma; a1 -= ma; c0 -= mb; c1 -= mb;
        const float vrr = wsum64(a0*a0 + a1*a1) * (1.f/128.f) + 1e-20f;
        const float vii = wsum64(c0*c0 + c1*c1) * (1.f/128.f) + 1e-20f;
        const float vri = wsum64(a0*c0 + a1*c1) * (1.f/128.f);
        const float s = sqrtf(fmaxf(vrr*vii - vri*vri, 0.f));
        const float t = sqrtf(vrr + vii + 2.f*s);
        const float inv = 1.f / (s*t);
        const float wrr = (vii + s)*inv, wii = (vrr + s)*inv, wri = -vri*inv;
        const float na0 = wrr*a0 + wri*c0, nb0 = wri*a0 + wii*c0;
        const float na1 = wrr*a1 + wri*c1, nb1 = wri*a1 + wii*c1;
        oA[lane][r]    = X2a[rowoff + lane]      + grr0*na0 + gri0*nb0 + br0;
        oA[lane+64][r] = X2a[rowoff + lane + 64] + grr1*na1 + gri1*nb1 + br1;
        oB[lane][r]    = X2b[rowoff + lane]      + gri0*na0 + gii0*nb0 + bi0;
        oB[lane+64][r] = X2b[rowoff + lane + 64] + gri1*na1 + gii1*nb1 + bi1;
    }
    __syncthreads();
    const size_t obase = ((size_t)b*Cc + h*Dd)*Mt + m0;
    for (int idx = tid; idx < 1024; idx += 256) {
        const int c = idx >> 3, jq = idx & 7;
        *(float4*)(OutA + obase + (size_t)c*Mt + jq*4) = *(const float4*)&oA[c][jq*4];
        *(float4*)(OutB + obase + (size_t)c*Mt + jq*4) = *(const float4*)&oB[c][jq*4];
    }
}

// ---------------------------------------------------------------------------
extern "C" void kernel_launch(void* const* d_in, const int* in_sizes, int n_in,
                              void* d_out, int out_size, void* d_ws, size_t ws_size,
                              hipStream_t stream)
{
    const float* xA0 = (const float*)d_in[0];
    const float* xB0 = (const float*)d_in[1];
    const float* wq  = (const float*)d_in[2];
    const float* bq  = (const float*)d_in[3];
    const float* wk  = (const float*)d_in[4];
    const float* bk  = (const float*)d_in[5];
    const float* wv  = (const float*)d_in[6];
    const float* bv  = (const float*)d_in[7];
    const float* dww = (const float*)d_in[8];
    const float* dwb = (const float*)d_in[9];
    const float* lng = (const float*)d_in[10];
    const float* lnb = (const float*)d_in[11];
    const float* pw  = (const float*)d_in[12];
    const float* f1wr = (const float*)d_in[13];
    const float* f1wi = (const float*)d_in[14];
    const float* f1br = (const float*)d_in[15];
    const float* f1bi = (const float*)d_in[16];
    const float* f2wr = (const float*)d_in[17];
    const float* f2wi = (const float*)d_in[18];
    const float* f2br = (const float*)d_in[19];
    const float* f2bi = (const float*)d_in[20];
    const float* lgrr = (const float*)d_in[21];
    const float* lgri = (const float*)d_in[22];
    const float* lgii = (const float*)d_in[23];
    const float* lbr  = (const float*)d_in[24];
    const float* lbi  = (const float*)d_in[25];
    const float* rpe  = (const float*)d_in[26];

    float* ws = (float*)d_ws;
    const size_t NB = (size_t)Bz * Cc * Mt;     // 16777216 floats (64 MB)
    const size_t SC = (size_t)Bz * Cc * NSs;    // 262144 floats (1 MB)
    float* Pa  = ws;        float* Pb  = Pa  + NB;
    float* Ra  = Pb  + NB;  float* Rb  = Ra  + NB;
    float* Ya  = Rb  + NB;  float* Yb  = Ya  + SC;
    float* XsA = Yb  + SC;  float* XsB = XsA + SC;
    float* Kab = XsB + SC;  float* Kbb = Kab + SC;
    float* Vab = Kbb + SC;  float* Vbb = Vab + SC;
    float* Sp0 = Vbb + SC;  float* Sp1 = Sp0 + SC;
    float* PosA = Sp1 + SC; float* PosB = PosA + (size_t)Bz*NSs*2;
    float* Wpf  = PosB + (size_t)Bz*NSs*2;       // ffn 4*16384 + wq 65536 u32

    uint* Qs  = (uint*)Ra;           // also used as Xt (input split) early on
    uint* Ktp = (uint*)Sp0;
    uint* Vsp = (uint*)Ya;
    uint* Wp  = (uint*)Wpf;                      // ffn weights (4 x 128x128)
    uint* Wqp = Wp + (size_t)4*Dd*Dd;            // wq (256x256)

    float* outAf = (float*)d_out;
    float* outBf = outAf + NB;

    for (int l = 0; l < LAYERS; l++) {
        const float* pwq = wq + (size_t)l*Cc*Cc;
        const float* pbq = bq + (size_t)l*Cc;
        const float* pwk = wk + (size_t)l*Cc*Cc;
        const float* pbk = bk + (size_t)l*Cc;
        const float* pwv = wv + (size_t)l*Cc*Cc;
        const float* pbv = bv + (size_t)l*Cc;
        const float* pdww = dww + (size_t)l*Cc*81;
        const float* pdwb = dwb + (size_t)l*Cc;
        const float* plng = lng + (size_t)l*Cc;
        const float* plnb = lnb + (size_t)l*Cc;
        const float* ppw  = pw  + (size_t)l*2*Cc;
        const float* p1wr = f1wr + (size_t)l*Dd*Dd;
        const float* p1wi = f1wi + (size_t)l*Dd*Dd;
        const float* p1br = f1br + (size_t)l*Dd;
        const float* p1bi = f1bi + (size_t)l*Dd;
        const float* p2wr = f2wr + (size_t)l*Dd*Dd;
        const float* p2wi = f2wi + (size_t)l*Dd*Dd;
        const float* p2br = f2br + (size_t)l*Dd;
        const float* p2bi = f2bi + (size_t)l*Dd;
        const float* g0rr = lgrr + (size_t)(l*2+0)*Dd;
        const float* g0ri = lgri + (size_t)(l*2+0)*Dd;
        const float* g0ii = lgii + (size_t)(l*2+0)*Dd;
        const float* g0br = lbr  + (size_t)(l*2+0)*Dd;
        const float* g0bi = lbi  + (size_t)(l*2+0)*Dd;
        const float* g1rr = lgrr + (size_t)(l*2+1)*Dd;
        const float* g1ri = lgri + (size_t)(l*2+1)*Dd;
        const float* g1ii = lgii + (size_t)(l*2+1)*Dd;
        const float* g1br = lbr  + (size_t)(l*2+1)*Dd;
        const float* g1bi = lbi  + (size_t)(l*2+1)*Dd;
        const float* prpe = rpe + (size_t)l*NHh*RPH*RPW;

        const float* inA = l ? outAf : xA0;
        const float* inB = l ? outBf : xB0;

        // weight packing for this layer (independent of everything else)
        dim3 gW(64, 4);
        k_wsplit4<<<gW, 256, 0, stream>>>(p1wr, p1wi, p2wr, p2wi, Wp);
        k_wsplit1<<<256, 256, 0, stream>>>(pwq, Wqp);

        // input split (token-major packed) -> Xt in Ra/Rb region
        dim3 gQs(Mt/64, BHt);
        k_qsplit<<<gQs, 256, 0, stream>>>(inA, inB, Qs);   // Qs == Xt here

        // Q projection via MFMA: Xt x Wq -> Pa/Pb ([c][m] f32)
        dim3 gPQ(Mt/64, Bz);
        k_projq_mfma<<<gPQ, 256, 0, stream>>>(Qs, Wqp, pbq, Pa, 0);
        k_projq_mfma<<<gPQ, 256, 0, stream>>>(Qs, Wqp, pbq, Pb, 1);

        dim3 gD(Cc, Bz);
        k_dwconv<<<gD, 256, 0, stream>>>(Pa, pdww, pdwb, Ya);
        k_dwconv<<<gD, 256, 0, stream>>>(Pb, pdww, pdwb, Yb);

        dim3 gL(NSs, Bz);
        k_lnpw<<<gL, 256, 0, stream>>>(Ya, plng, plnb, ppw, PosA);
        k_lnpw<<<gL, 256, 0, stream>>>(Yb, plng, plnb, ppw, PosB);

        dim3 gS(Cc, Bz);
        k_gsample<<<gS, 256, 0, stream>>>(inA, PosA, XsA);
        k_gsample<<<gS, 256, 0, stream>>>(inB, PosB, XsB);

        dim3 gKV(NSs/64, Cc/64, Bz);
        k_proj<<<gKV, 256, 0, stream>>>(XsA, pwk, pbk, Kab, NSs);
        k_proj<<<gKV, 256, 0, stream>>>(XsB, pwk, pbk, Kbb, NSs);
        k_proj<<<gKV, 256, 0, stream>>>(XsA, pwv, pbv, Vab, NSs);
        k_proj<<<gKV, 256, 0, stream>>>(XsB, pwv, pbv, Vbb, NSs);

        // packed bf16-pair pre-splits (Ya/Yb dead after k_lnpw)
        dim3 gKs(NSs/64, BHt);
        k_ksplit<<<gKs, 256, 0, stream>>>(Kab, Kbb, Ktp);
        k_vsplit<<<2048, 256, 0, stream>>>(Vab, Vbb, Vsp);
        // Q split (overwrites Xt -- dead after projq)
        k_qsplit<<<gQs, 256, 0, stream>>>(Pa, Pb, Qs);

        // attn: Qs(R) -> O(P).  Qs dead afterwards.
        dim3 gA(Mt/64, BHt);
        k_attn_mfma<<<gA, 256, 0, stream>>>(Qs, Ktp, Vsp, PosA, prpe, Pa, Pb);

        // cln_attn: O(P) + X(in) -> X2(R).
        dim3 gC(Mt/32, BHt);
        k_cln_attn<<<gC, 256, 0, stream>>>(Pa, Pb, inA, inB,
                                           g0rr, g0ri, g0ii, g0br, g0bi, Ra, Rb);

        // fc1: X2(R) -> H1(P); fc2: H1(P) -> H2(P) in-place.  (MFMA hi/lo)
        dim3 gF((unsigned)((size_t)BHt*Mt/64));
        k_ffn_mfma<<<gF, 256, 0, stream>>>(Ra, Rb, Wp, Wp + (size_t)Dd*Dd,
                                           p1br, p1bi, Pa, Pb, 1);
        k_ffn_mfma<<<gF, 256, 0, stream>>>(Pa, Pb, Wp + (size_t)2*Dd*Dd,
                                           Wp + (size_t)3*Dd*Dd,
                                           p2br, p2bi, Pa, Pb, 0);

        // cln_ffn: H2(P) + X2(R) -> layer output
        k_cln_ffn<<<gC, 256, 0, stream>>>(Pa, Pb, Ra, Rb,
                                          g1rr, g1ri, g1ii, g1br, g1bi, outAf, outBf);
    }
    (void)in_sizes; (void)n_in; (void)out_size; (void)ws_size;
}

// Round 9
// 2557.994 us; speedup vs baseline: 1.1198x; 1.1198x over previous
//
#include <hip/hip_runtime.h>
#include <math.h>

#define DEVFN static __device__ __forceinline__

constexpr int LAYERS = 2;
constexpr int Bz = 4;
constexpr int Cc = 256;
constexpr int Hh = 128;
constexpr int Ww = 128;
constexpr int Dd = 128;
constexpr int NHh = 2;
constexpr int BHt = Bz * NHh;              // 8
constexpr int Mt  = Hh * Ww;               // 16384
constexpr int HK = 16, WK = 16;
constexpr int NSs = HK * WK;               // 256
constexpr int STR = 8, PADc = 4;
constexpr int RPH = 2*Hh - 1, RPW = 2*Ww - 1;  // 255
constexpr float SCALE_F = 0.17677669529663687f; // 32^-0.5

typedef __attribute__((ext_vector_type(8))) short  bf16x8;
typedef __attribute__((ext_vector_type(4))) float  f32x4;

DEVFN float wsum64(float v) {
    #pragma unroll
    for (int off = 32; off > 0; off >>= 1) v += __shfl_xor(v, off, 64);
    return v;
}

// fp32 -> bf16 hi + bf16 lo (RNE both); x ~= hi + lo with ~2^-17 rel error.
DEVFN void split2(float x, ushort& h, ushort& l)
{
    const uint u  = __float_as_uint(x);
    const uint hb = (u + 0x7fffu + ((u >> 16) & 1u)) & 0xffff0000u;
    h = (ushort)(hb >> 16);
    const float r = x - __uint_as_float(hb);
    const uint ul = __float_as_uint(r);
    l = (ushort)((ul + 0x7fffu + ((ul >> 16) & 1u)) >> 16);
}

DEVFN ushort f2bf(float x)
{
    const uint u = __float_as_uint(x);
    return (ushort)((u + 0x7fffu + ((u >> 16) & 1u)) >> 16);
}
DEVFN float bf2f(ushort s) { return __uint_as_float(((uint)s) << 16); }

DEVFN uint shfu(uint v, int src) { return (uint)__shfl((int)v, src, 64); }

DEVFN bf16x8 pack4(uint a, uint b, uint c, uint d)
{
    union { uint u[4]; bf16x8 v; } t;
    t.u[0] = a; t.u[1] = b; t.u[2] = c; t.u[3] = d;
    return t.v;
}

// unpack 8 packed words (hi<<16|lo) into hi/lo bf16x8 fragments
DEVFN void unpack8(uint4 a, uint4 b, bf16x8& h, bf16x8& l)
{
    const uint u[8] = {a.x, a.y, a.z, a.w, b.x, b.y, b.z, b.w};
    #pragma unroll
    for (int j = 0; j < 8; j++) {
        h[j] = (short)(u[j] >> 16);
        l[j] = (short)(u[j] & 0xffffu);
    }
}

// ---------------------------------------------------------------------------
// Generic 1x1-conv projection (fp32 VALU): used only for the small K/V
// projections (Mdim = NSs = 256).
// grid (Mdim/64, Cc/64, Bz), block 256
// ---------------------------------------------------------------------------
__global__ __launch_bounds__(256)
void k_proj(const float* __restrict__ X, const float* __restrict__ W,
            const float* __restrict__ bias, float* __restrict__ Out, int Mdim)
{
    __shared__ float wsm[16][64];
    __shared__ float xsm[16][64];
    const int tid = threadIdx.x;
    const int m0 = blockIdx.x * 64;
    const int o0 = blockIdx.y * 64;
    const float* Xb = X + (size_t)blockIdx.z * Cc * Mdim;
    float* Ob = Out + (size_t)blockIdx.z * Cc * Mdim;
    const int to = tid >> 4;   // 0..15 (o sub /4)
    const int tm = tid & 15;   // 0..15 (m sub /4)
    float acc[4][4] = {{0.f}};
    for (int k0 = 0; k0 < Cc; k0 += 16) {
        {
            const int i = tid >> 2, kq = tid & 3;
            float4 w4 = *(const float4*)(W + (size_t)(o0 + i)*Cc + k0 + kq*4);
            wsm[kq*4+0][i] = w4.x; wsm[kq*4+1][i] = w4.y;
            wsm[kq*4+2][i] = w4.z; wsm[kq*4+3][i] = w4.w;
            const int kk = tid >> 4, jq = tid & 15;
            *(float4*)&xsm[kk][jq*4] =
                *(const float4*)(Xb + (size_t)(k0 + kk)*Mdim + m0 + jq*4);
        }
        __syncthreads();
        #pragma unroll
        for (int kk = 0; kk < 16; kk++) {
            float4 a4 = *(const float4*)&wsm[kk][to*4];
            float4 b4 = *(const float4*)&xsm[kk][tm*4];
            float av[4] = {a4.x, a4.y, a4.z, a4.w};
            float bv[4] = {b4.x, b4.y, b4.z, b4.w};
            #pragma unroll
            for (int ii = 0; ii < 4; ii++)
                #pragma unroll
                for (int jj = 0; jj < 4; jj++)
                    acc[ii][jj] += av[ii] * bv[jj];
        }
        __syncthreads();
    }
    #pragma unroll
    for (int ii = 0; ii < 4; ii++) {
        const int o = o0 + to*4 + ii;
        const float bo = bias[o];
        float4 r4 = make_float4(acc[ii][0]+bo, acc[ii][1]+bo, acc[ii][2]+bo, acc[ii][3]+bo);
        *(float4*)(Ob + (size_t)o*Mdim + m0 + tm*4) = r4;
    }
}

// ---------------------------------------------------------------------------
// MFMA 1x1-conv projection for the big Q GEMM (hi/lo bf16 split), v2:
// LDS-staged weights (attn-v4 pattern).
//   Out[b][o][m] = sum_c Wq[o][c] * X_s[b][c][m] + bias[o]   (one stream s)
// Wq consumed in 16KB chunks (16 output rows), double-buffered in LDS with
// the same swizzled stage/read addressing as attn's K loop.  The output
// transpose buffer is UNIONed with the staging buffer (staging is dead after
// the final k-loop barrier) -> LDS 68KB, 2 blocks/CU.
// grid (Mt/64, Bz), block 256
// ---------------------------------------------------------------------------
__global__ __launch_bounds__(256, 2)
void k_projq_mfma(const uint* __restrict__ Xt, const uint* __restrict__ Wqp,
                  const float* __restrict__ bias, float* __restrict__ Out,
                  int s)
{
    __shared__ __align__(16) char smem[256 * 68 * 4];   // 69632 B (union)
    char* const kv0 = smem;                  // staging dbuf: 2 x 16KB
    char* const kv1 = smem + 16384;
    float* const ot = (float*)smem;          // epilogue transpose (69632 B)
    const int tid = threadIdx.x;
    const int m0 = blockIdx.x * 64;
    const int b  = blockIdx.y;
    const int w = tid >> 6, l = tid & 63;
    const int l15 = l & 15, g = l >> 4;
    const int m = m0 + w*16 + l15;

    auto stage = [&](int p, const uint* chunk) {
        char* dst = p ? kv1 : kv0;
        #pragma unroll
        for (int r = 0; r < 4; r++) {
            const int idx = r*1024 + tid*4;              // u32 index in chunk
            const uint4 v = *(const uint4*)(chunk + idx);
            const int byte = idx << 2;
            const int swz = ((byte >> 10) & 7) << 4;
            *(uint4*)(dst + (byte ^ swz)) = v;
        }
    };

    // ---- B fragments: X token column m, channels c = cs*32 + g*8 + j
    bf16x8 xh[8], xl[8];
    {
        const uint* xp0 = Xt + ((size_t)(b*2 + 0)*Mt + m)*256 + s*128 + g*8;
        const uint* xp1 = Xt + ((size_t)(b*2 + 1)*Mt + m)*256 + s*128 + g*8;
        #pragma unroll
        for (int cs = 0; cs < 8; cs++) {
            const uint* xp = ((cs < 4) ? xp0 : xp1) + (cs & 3)*32;
            const uint4 x0 = *(const uint4*)(xp);
            const uint4 x1 = *(const uint4*)(xp + 4);
            unpack8(x0, x1, xh[cs], xl[cs]);
        }
    }

    // ---- MFMA with staged W: acc[nt] holds Out[o = nt*16 + g*4 + r][m]
    f32x4 acc[16];
    #pragma unroll
    for (int nt = 0; nt < 16; nt++) acc[nt] = (f32x4){0.f, 0.f, 0.f, 0.f};

    const int rowb = l15 << 10;
    const int sw = (l15 & 7) << 4;

    stage(0, Wqp);
    __syncthreads();                       // chunk 0 ready
    #pragma unroll
    for (int nt = 0; nt < 16; nt++) {
        if (nt < 15) stage((nt + 1) & 1, Wqp + (nt + 1)*4096);
        const char* bufc = (nt & 1) ? kv1 : kv0;
        #pragma unroll
        for (int cs = 0; cs < 8; cs++) {
            const int a0 = rowb + cs*128 + g*32;
            const uint4 w0 = *(const uint4*)(bufc + (a0 ^ sw));
            const uint4 w1 = *(const uint4*)(bufc + ((a0 + 16) ^ sw));
            bf16x8 wh, wl; unpack8(w0, w1, wh, wl);
            acc[nt] = __builtin_amdgcn_mfma_f32_16x16x32_bf16(wh, xh[cs], acc[nt], 0, 0, 0);
            acc[nt] = __builtin_amdgcn_mfma_f32_16x16x32_bf16(wh, xl[cs], acc[nt], 0, 0, 0);
            acc[nt] = __builtin_amdgcn_mfma_f32_16x16x32_bf16(wl, xh[cs], acc[nt], 0, 0, 0);
        }
        __syncthreads();                   // next chunk landed; buf free
    }

    // ---- epilogue: bias, LDS transpose (reuses staging region -- safe:
    // all staging reads completed at the loop's final barrier), coalesced
    // [o][m] stores.
    #pragma unroll
    for (int nt = 0; nt < 16; nt++) {
        #pragma unroll
        for (int r = 0; r < 4; r++) {
            const int o = nt*16 + g*4 + r;
            ot[o*68 + w*16 + l15] = acc[nt][r] + bias[o];
        }
    }
    __syncthreads();
    #pragma unroll
    for (int it = 0; it < 16; it++) {
        const int idx = it*256 + tid;      // 0..4095 float4s
        const int o = idx >> 4, mq = idx & 15;
        const float4 v = *(const float4*)&ot[o*68 + mq*4];
        *(float4*)(Out + ((size_t)b*Cc + o)*Mt + m0 + mq*4) = v;
    }
}

// ---------------------------------------------------------------------------
// Depthwise 9x9 stride-8 pad-4 conv: Y[b,c,i,j], grid (Cc, Bz), block 256
// ---------------------------------------------------------------------------
__global__ __launch_bounds__(256)
void k_dwconv(const float* __restrict__ Q, const float* __restrict__ Wdw,
              const float* __restrict__ Bdw, float* __restrict__ Y)
{
    const int c = blockIdx.x, b = blockIdx.y;
    __shared__ float wsmem[81];
    const int tid = threadIdx.x;
    if (tid < 81) wsmem[tid] = Wdw[c*81 + tid];
    __syncthreads();
    const int i = tid >> 4, j = tid & 15;
    const float* Qc = Q + ((size_t)b*Cc + c)*Mt;
    float acc = Bdw[c];
    const int ybase = i*STR - PADc, xbase = j*STR - PADc;
    #pragma unroll
    for (int u = 0; u < 9; u++) {
        const int y = ybase + u;
        if (y < 0 || y >= Hh) continue;
        #pragma unroll
        for (int v = 0; v < 9; v++) {
            const int x = xbase + v;
            if (x < 0 || x >= Ww) continue;
            acc += wsmem[u*9+v] * Qc[y*Ww + x];
        }
    }
    Y[((size_t)b*Cc + c)*NSs + i*WK + j] = acc;
}

// ---------------------------------------------------------------------------
// Channel-LN + exact GELU + pointwise(2) + ref grid -> Pos[b,s,2]
// grid (NSs, Bz), block 256 (tid = channel)
// ---------------------------------------------------------------------------
DEVFN float block_reduce(float v, float* red, int tid)
{
    red[tid] = v; __syncthreads();
    #pragma unroll
    for (int s2 = 128; s2 > 0; s2 >>= 1) {
        if (tid < s2) red[tid] += red[tid + s2];
        __syncthreads();
    }
    const float r = red[0];
    __syncthreads();
    return r;
}

__global__ __launch_bounds__(256)
void k_lnpw(const float* __restrict__ Y, const float* __restrict__ G,
            const float* __restrict__ Bt, const float* __restrict__ PW,
            float* __restrict__ Pos)
{
    __shared__ float red[256];
    const int ij = blockIdx.x, b = blockIdx.y;
    const int tid = threadIdx.x;
    const float y = Y[((size_t)b*Cc + tid)*NSs + ij];
    const float m = block_reduce(y, red, tid) * (1.f/256.f);
    const float d = y - m;
    const float v = block_reduce(d*d, red, tid) * (1.f/256.f);
    const float g = d * rsqrtf(v + 1e-5f) * G[tid] + Bt[tid];
    const float ge = 0.5f * g * (1.f + erff(g * 0.70710678118654752f));
    const float off0 = block_reduce(ge * PW[tid], red, tid);
    const float off1 = block_reduce(ge * PW[Cc + tid], red, tid);
    if (tid == 0) {
        const int i = ij >> 4, j = ij & 15;
        const float refy = ((float)i + 0.5f) * (2.f/15.f) - 1.f;
        const float refx = ((float)j + 0.5f) * (2.f/15.f) - 1.f;
        Pos[((size_t)b*NSs + ij)*2 + 0] = off0 + refy;
        Pos[((size_t)b*NSs + ij)*2 + 1] = off1 + refx;
    }
}

// ---------------------------------------------------------------------------
// Bilinear grid sample (zero padding): Xs[b,c,s] = bilerp(X[b,c], Pos[b,s])
// grid (Cc, Bz), block 256 (tid = sample index s)
// ---------------------------------------------------------------------------
__global__ __launch_bounds__(256)
void k_gsample(const float* __restrict__ X, const float* __restrict__ Pos,
               float* __restrict__ Xs)
{
    const int c = blockIdx.x, b = blockIdx.y, s = threadIdx.x;
    const float py = Pos[((size_t)b*NSs + s)*2 + 0];
    const float px = Pos[((size_t)b*NSs + s)*2 + 1];
    const float x = (px + 1.f) * 0.5f * (float)(Ww - 1);
    const float y = (py + 1.f) * 0.5f * (float)(Hh - 1);
    const float x0 = floorf(x), y0 = floorf(y);
    const float wx1 = x - x0, wx0 = 1.f - wx1;
    const float wy1 = y - y0, wy0 = 1.f - wy1;
    const float* Xc = X + ((size_t)b*Cc + c)*Mt;
    float acc = 0.f;
    #pragma unroll
    for (int t = 0; t < 4; t++) {
        const float xx = x0 + (float)(t & 1);
        const float yy = y0 + (float)(t >> 1);
        float w = ((t & 1) ? wx1 : wx0) * ((t >> 1) ? wy1 : wy0);
        const bool valid = (xx >= 0.f) && (xx <= (float)(Ww-1)) &&
                           (yy >= 0.f) && (yy <= (float)(Hh-1));
        const int xi = (int)fminf(fmaxf(xx, 0.f), (float)(Ww-1));
        const int yi = (int)fminf(fmaxf(yy, 0.f), (float)(Hh-1));
        acc += (valid ? w : 0.f) * Xc[yi*Ww + xi];
    }
    Xs[((size_t)b*Cc + c)*NSs + s] = acc;
}

// ---------------------------------------------------------------------------
// Split+transpose pre-pass: pair of fp32 [b][c][m] -> packed u32 (hi<<16|lo)
// Out[bh][m][cc2], cc2 = stream-a ch 0..127, stream-b ch 128..255.
// Used for both the layer input (Xt) and the computed Q (Qs).
// grid (Mt/64, BHt), block 256
// ---------------------------------------------------------------------------
__global__ __launch_bounds__(256)
void k_qsplit(const float* __restrict__ Qa, const float* __restrict__ Qb,
              uint* __restrict__ Qs)
{
    __shared__ float tile[64][65];
    const int tid = threadIdx.x;
    const int m0 = blockIdx.x * 64;
    const int bh = blockIdx.y;
    const int b = bh >> 1, h = bh & 1;
    for (int ccblk = 0; ccblk < 4; ccblk++) {
        #pragma unroll
        for (int i = 0; i < 4; i++) {
            const int idx = i*256 + tid;           // 0..1023
            const int ccl = idx >> 4, mq = idx & 15;
            const int cc2 = ccblk*64 + ccl;
            const float* src = (cc2 >> 7) ? Qb : Qa;
            *(float4*)&tile[ccl][mq*4] =
                *(const float4*)(src + ((size_t)b*Cc + h*Dd + (cc2 & 127))*Mt + m0 + mq*4);
        }
        __syncthreads();
        #pragma unroll
        for (int i = 0; i < 16; i++) {
            const int idx = i*256 + tid;
            const int ml = idx >> 6, ccl = idx & 63;
            ushort hi, lo; split2(tile[ccl][ml], hi, lo);
            Qs[((size_t)bh*Mt + m0 + ml)*256 + ccblk*64 + ccl] = ((uint)hi << 16) | lo;
        }
        __syncthreads();
    }
}

// ---------------------------------------------------------------------------
// K split+transpose pre-pass: K fp32 [b][c][n] -> packed u32 Ktp[bh][n][cc2]
// grid (NSs/64, BHt), block 256
// ---------------------------------------------------------------------------
__global__ __launch_bounds__(256)
void k_ksplit(const float* __restrict__ Ka, const float* __restrict__ Kb,
              uint* __restrict__ Ktp)
{
    __shared__ float tile[64][65];
    const int tid = threadIdx.x;
    const int n0 = blockIdx.x * 64;
    const int bh = blockIdx.y;
    const int b = bh >> 1, h = bh & 1;
    for (int ccblk = 0; ccblk < 4; ccblk++) {
        #pragma unroll
        for (int i = 0; i < 16; i++) {
            const int idx = i*256 + tid;
            const int ccl = idx >> 6, nl = idx & 63;
            const int cc2 = ccblk*64 + ccl;
            const float* src = (cc2 >> 7) ? Kb : Ka;
            tile[ccl][nl] = src[((size_t)b*Cc + h*Dd + (cc2 & 127))*NSs + n0 + nl];
        }
        __syncthreads();
        #pragma unroll
        for (int i = 0; i < 16; i++) {
            const int idx = i*256 + tid;
            const int nl = idx >> 6, ccl = idx & 63;
            ushort hi, lo; split2(tile[ccl][nl], hi, lo);
            Ktp[((size_t)bh*NSs + n0 + nl)*256 + ccblk*64 + ccl] = ((uint)hi << 16) | lo;
        }
        __syncthreads();
    }
}

// ---------------------------------------------------------------------------
// V split pre-pass: V fp32 [b][c][n] -> packed u32 Vsp[bh][j][n]
// grid (2048), block 256
// ---------------------------------------------------------------------------
__global__ __launch_bounds__(256)
void k_vsplit(const float* __restrict__ Va, const float* __restrict__ Vb,
              uint* __restrict__ Vsp)
{
    const size_t e = (size_t)blockIdx.x*256 + threadIdx.x;
    const int n  = (int)(e & 255);
    const int j  = (int)((e >> 8) & 255);
    const int bh = (int)(e >> 16);
    const int b = bh >> 1, h = bh & 1;
    const float* src = (j >> 7) ? Vb : Va;
    const float v = src[((size_t)b*Cc + h*Dd + (j & 127))*NSs + n];
    ushort hi, lo; split2(v, hi, lo);
    Vsp[e] = ((uint)hi << 16) | lo;
}

// ---------------------------------------------------------------------------
// FFN weight pack pre-pass: 4 matrices (128x128, row-major [o][k]) -> packed
// u32 (hi<<16|lo).  grid (64, 4), block 256.
// ---------------------------------------------------------------------------
__global__ __launch_bounds__(256)
void k_wsplit4(const float* __restrict__ W0, const float* __restrict__ W1,
               const float* __restrict__ W2, const float* __restrict__ W3,
               uint* __restrict__ Wp)
{
    const int mat = blockIdx.y;
    const float* W = (mat == 0) ? W0 : (mat == 1) ? W1 : (mat == 2) ? W2 : W3;
    const int i = blockIdx.x*256 + threadIdx.x;   // 0..16383
    ushort hi, lo; split2(W[i], hi, lo);
    Wp[(size_t)mat*Dd*Dd + i] = ((uint)hi << 16) | lo;
}

// ---------------------------------------------------------------------------
// Single 256x256 weight pack (wq): grid (256), block 256.
// ---------------------------------------------------------------------------
__global__ __launch_bounds__(256)
void k_wsplit1(const float* __restrict__ W, uint* __restrict__ Wp)
{
    const int i = blockIdx.x*256 + threadIdx.x;   // 0..65535
    ushort hi, lo; split2(W[i], hi, lo);
    Wp[i] = ((uint)hi << 16) | lo;
}

// ---------------------------------------------------------------------------
// MFMA attention v4 (validated round 7; unchanged this round).
// grid (Mt/64, BHt), block 256
// ---------------------------------------------------------------------------
__global__ __launch_bounds__(256, 2)
void k_attn_mfma(const uint* __restrict__ Qs, const uint* __restrict__ Ktp,
                 const uint* __restrict__ Vsp,
                 const float* __restrict__ Pos, const float* __restrict__ Rpe,
                 float* __restrict__ Oa, float* __restrict__ Ob)
{
    constexpr int GS = 66;                 // 65 entries + 1 pad
    __shared__ ushort Gt[NSs * GS];        // 33792 B (bf16)
    __shared__ float fxs[NSs];             // 1024 B
    __shared__ __align__(16) uint kvbuf[2][4096];   // 2 x 16KB staging dbuf
    const int tid = threadIdx.x;
    const int m0 = blockIdx.x * 64;
    const int bh = blockIdx.y;
    const int b = bh >> 1, h = bh & 1;
    const int j0 = m0 & 127;               // jq base for this block
    const int iq = m0 >> 7;                // constant over the block
    const float* Rh = Rpe + (size_t)h * RPH * RPW;

    // ---- G-table build: thread n handles sample n (contiguous row reads)
    {
        const int n = tid;
        const float py = Pos[((size_t)b*NSs + n)*2 + 0];
        const float px = Pos[((size_t)b*NSs + n)*2 + 1];
        const float xf = (float)j0 + 63.5f - 63.5f*px;   // x(m) = xf + dm
        const float yf = (float)iq + 63.5f - 63.5f*py;   // y const over block
        const float xbf = floorf(xf), ybf = floorf(yf);
        const float fx = xf - xbf, fy = yf - ybf;
        fxs[n] = fx;
        const int yb = (int)ybf;
        const float wy0 = (1.f - fy) * ((yb   >= 0 && yb   <= RPH-1) ? 1.f : 0.f);
        const float wy1 = fy         * ((yb+1 >= 0 && yb+1 <= RPH-1) ? 1.f : 0.f);
        const int y0c = yb   < 0 ? 0 : (yb   > RPH-1 ? RPH-1 : yb);
        const int y1c = yb+1 < 0 ? 0 : (yb+1 > RPH-1 ? RPH-1 : yb+1);
        const float* r0 = Rh + (size_t)y0c * RPW;
        const float* r1 = Rh + (size_t)y1c * RPW;
        const int xb = (int)xbf;
        #pragma unroll 4
        for (int t = 0; t <= 64; t++) {
            const int xi = xb + t;
            const int xc = xi < 0 ? 0 : (xi > RPW-1 ? RPW-1 : xi);
            const float v = wy0*r0[xc] + wy1*r1[xc];
            Gt[n*GS + t] = f2bf((xi >= 0 && xi <= RPW-1) ? v : 0.f);
        }
    }

    const int w = tid >> 6, l = tid & 63;
    const int l15 = l & 15, g = l >> 4;
    const int mcol = m0 + w*16 + l15;      // this lane's output column m

    // staging: copy one 16KB chunk (16 rows x 1KB) into kvbuf[p], swizzled.
    const uint* kbase = Ktp + (size_t)bh * 65536;
    const uint* vbase = Vsp + (size_t)bh * 65536;
    char* const kv0 = (char*)&kvbuf[0][0];
    char* const kv1 = (char*)&kvbuf[1][0];
    auto stage = [&](int p, const uint* chunk) {
        char* dst = p ? kv1 : kv0;
        #pragma unroll
        for (int r = 0; r < 4; r++) {
            const int idx = r*1024 + tid*4;              // u32 index in chunk
            const uint4 v = *(const uint4*)(chunk + idx);
            const int byte = idx << 2;
            const int swz = ((byte >> 10) & 7) << 4;
            *(uint4*)(dst + (byte ^ swz)) = v;
        }
    };

    // ---- Q fragments -> registers, unpacked once (64 VGPR)
    bf16x8 qh[8], ql[8];
    {
        const uint* qp = Qs + ((size_t)bh*Mt + mcol)*256 + g*8;
        #pragma unroll
        for (int cs = 0; cs < 8; cs++) {
            const uint4 q0 = *(const uint4*)(qp + cs*32);
            const uint4 q1 = *(const uint4*)(qp + cs*32 + 4);
            unpack8(q0, q1, qh[cs], ql[cs]);
        }
    }

    // ---- QK^T with staged K: acc[nt] = S[n = nt*16+g*4+r][m = mcol]
    f32x4 acc[16];
    #pragma unroll
    for (int nt = 0; nt < 16; nt++) acc[nt] = (f32x4){0.f, 0.f, 0.f, 0.f};

    const int rowb = l15 << 10;
    const int sw = (l15 & 7) << 4;

    stage(0, kbase);
    __syncthreads();                       // chunk 0 ready (+ Gt/fxs ready)
    #pragma unroll
    for (int nt = 0; nt < 16; nt++) {
        if (nt < 15) stage((nt + 1) & 1, kbase + (nt + 1)*4096);
        const char* bufc = (nt & 1) ? kv1 : kv0;
        #pragma unroll
        for (int cs = 0; cs < 8; cs++) {
            const int a0 = rowb + cs*128 + g*32;
            const uint4 k0 = *(const uint4*)(bufc + (a0 ^ sw));
            const uint4 k1 = *(const uint4*)(bufc + ((a0 + 16) ^ sw));
            bf16x8 kh, kl; unpack8(k0, k1, kh, kl);
            acc[nt] = __builtin_amdgcn_mfma_f32_16x16x32_bf16(kh, qh[cs], acc[nt], 0, 0, 0);
            acc[nt] = __builtin_amdgcn_mfma_f32_16x16x32_bf16(kh, ql[cs], acc[nt], 0, 0, 0);
            acc[nt] = __builtin_amdgcn_mfma_f32_16x16x32_bf16(kl, qh[cs], acc[nt], 0, 0, 0);
        }
        __syncthreads();                   // next chunk landed; buf free
    }

    // ---- bias + softmax (row m is wave-local across the 4 g-lanes)
    const int dm = w*16 + l15;
    float mx = -1e30f;
    #pragma unroll
    for (int nt = 0; nt < 16; nt++) {
        #pragma unroll
        for (int r = 0; r < 4; r++) {
            const int n = nt*16 + g*4 + r;
            const float g0 = bf2f(Gt[n*GS + dm]);
            const float g1 = bf2f(Gt[n*GS + dm + 1]);
            const float bias = g0 + fxs[n]*(g1 - g0);
            const float s = SCALE_F*acc[nt][r] + bias;
            acc[nt][r] = s;
            mx = fmaxf(mx, s);
        }
    }
    mx = fmaxf(mx, __shfl_xor(mx, 16, 64));
    mx = fmaxf(mx, __shfl_xor(mx, 32, 64));
    float sum = 0.f;
    #pragma unroll
    for (int nt = 0; nt < 16; nt++)
        #pragma unroll
        for (int r = 0; r < 4; r++) {
            const float e = __expf(acc[nt][r] - mx);
            acc[nt][r] = e;
            sum += e;
        }
    sum += __shfl_xor(sum, 16, 64);
    sum += __shfl_xor(sum, 32, 64);
    const float inv = 1.f / sum;

    // ---- pack P to bf16 hi/lo word pairs (per nt: words [r0|r1], [r2|r3])
    uint hU0[16], hU1[16], lU0[16], lU1[16];
    #pragma unroll
    for (int nt = 0; nt < 16; nt++) {
        ushort ph_[4], pl_[4];
        #pragma unroll
        for (int r = 0; r < 4; r++) split2(acc[nt][r] * inv, ph_[r], pl_[r]);
        hU0[nt] = (uint)ph_[0] | ((uint)ph_[1] << 16);
        hU1[nt] = (uint)ph_[2] | ((uint)ph_[3] << 16);
        lU0[nt] = (uint)pl_[0] | ((uint)pl_[1] << 16);
        lU1[nt] = (uint)pl_[2] | ((uint)pl_[3] << 16);
    }

    // ---- shuffle-precompute PV A-fragments (identical across jt)
    const int srcA = (((2*g)     & 3) << 4) | l15;
    const int srcB = (((2*g + 1) & 3) << 4) | l15;
    const bool hi2 = (g >> 1) & 1;
    bf16x8 ph[8], pl[8];
    #pragma unroll
    for (int cs = 0; cs < 8; cs++) {
        uint A00 = shfu(hU0[2*cs], srcA), A01 = shfu(hU0[2*cs+1], srcA);
        uint A10 = shfu(hU1[2*cs], srcA), A11 = shfu(hU1[2*cs+1], srcA);
        uint B00 = shfu(hU0[2*cs], srcB), B01 = shfu(hU0[2*cs+1], srcB);
        uint B10 = shfu(hU1[2*cs], srcB), B11 = shfu(hU1[2*cs+1], srcB);
        ph[cs] = pack4(hi2 ? A01 : A00, hi2 ? A11 : A10,
                       hi2 ? B01 : B00, hi2 ? B11 : B10);
        A00 = shfu(lU0[2*cs], srcA); A01 = shfu(lU0[2*cs+1], srcA);
        A10 = shfu(lU1[2*cs], srcA); A11 = shfu(lU1[2*cs+1], srcA);
        B00 = shfu(lU0[2*cs], srcB); B01 = shfu(lU0[2*cs+1], srcB);
        B10 = shfu(lU1[2*cs], srcB); B11 = shfu(lU1[2*cs+1], srcB);
        pl[cs] = pack4(hi2 ? A01 : A00, hi2 ? A11 : A10,
                       hi2 ? B01 : B00, hi2 ? B11 : B10);
    }

    // ---- PV with staged V, jt-outer (per-jt f32x4 accumulator)
    const size_t rowbase = ((size_t)bh*Mt + mcol)*Dd;
    stage(0, vbase);                       // kvbuf[0] free: QK done (barrier)
    __syncthreads();
    for (int jt = 0; jt < 16; jt++) {
        if (jt < 15) stage((jt + 1) & 1, vbase + (jt + 1)*4096);
        const char* bufc = (jt & 1) ? kv1 : kv0;
        f32x4 a2 = (f32x4){0.f, 0.f, 0.f, 0.f};
        #pragma unroll
        for (int cs = 0; cs < 8; cs++) {
            const int a0 = rowb + cs*128 + g*32;
            const uint4 v0 = *(const uint4*)(bufc + (a0 ^ sw));
            const uint4 v1 = *(const uint4*)(bufc + ((a0 + 16) ^ sw));
            bf16x8 vh, vl; unpack8(v0, v1, vh, vl);
            a2 = __builtin_amdgcn_mfma_f32_16x16x32_bf16(vh, ph[cs], a2, 0, 0, 0);
            a2 = __builtin_amdgcn_mfma_f32_16x16x32_bf16(vh, pl[cs], a2, 0, 0, 0);
            a2 = __builtin_amdgcn_mfma_f32_16x16x32_bf16(vl, ph[cs], a2, 0, 0, 0);
        }
        const float4 o = make_float4(a2[0], a2[1], a2[2], a2[3]);
        const int jv0 = jt*16 + g*4;
        if (jt < 8) *(float4*)(Oa + rowbase + jv0) = o;
        else        *(float4*)(Ob + rowbase + jv0 - 128) = o;
        __syncthreads();
    }
}

// ---------------------------------------------------------------------------
// Complex whitening LN (attention branch) + residual from (B,C,M) input.
// grid (Mt/32, BHt), block 256. X2 written token-major.
// ---------------------------------------------------------------------------
__global__ __launch_bounds__(256)
void k_cln_attn(const float* __restrict__ Oa, const float* __restrict__ Ob,
                const float* __restrict__ Xa, const float* __restrict__ Xb,
                const float* __restrict__ Pgrr, const float* __restrict__ Pgri,
                const float* __restrict__ Pgii, const float* __restrict__ Pbr,
                const float* __restrict__ Pbi,
                float* __restrict__ X2a, float* __restrict__ X2b)
{
    __shared__ float ra[32][132];
    __shared__ float rb[32][132];
    const int tid = threadIdx.x;
    const int m0 = blockIdx.x * 32;
    const int bh = blockIdx.y;
    const int b = bh >> 1, h = bh & 1;
    {
        const float* Xpa = Xa + ((size_t)b*Cc + h*Dd)*Mt + m0;
        const float* Xpb = Xb + ((size_t)b*Cc + h*Dd)*Mt + m0;
        for (int idx = tid; idx < 1024; idx += 256) {
            const int c = idx >> 3, jq = idx & 7;
            float4 a4 = *(const float4*)(Xpa + (size_t)c*Mt + jq*4);
            float4 b4 = *(const float4*)(Xpb + (size_t)c*Mt + jq*4);
            ra[jq*4+0][c] = a4.x; ra[jq*4+1][c] = a4.y;
            ra[jq*4+2][c] = a4.z; ra[jq*4+3][c] = a4.w;
            rb[jq*4+0][c] = b4.x; rb[jq*4+1][c] = b4.y;
            rb[jq*4+2][c] = b4.z; rb[jq*4+3][c] = b4.w;
        }
    }
    __syncthreads();
    const int wave = tid >> 6, lane = tid & 63;
    const float grr0 = Pgrr[lane], grr1 = Pgrr[lane+64];
    const float gri0 = Pgri[lane], gri1 = Pgri[lane+64];
    const float gii0 = Pgii[lane], gii1 = Pgii[lane+64];
    const float br0  = Pbr[lane],  br1  = Pbr[lane+64];
    const float bi0  = Pbi[lane],  bi1  = Pbi[lane+64];
    for (int r = wave; r < 32; r += 4) {
        const size_t rowoff = ((size_t)bh*Mt + m0 + r)*Dd;
        float a0 = Oa[rowoff + lane], a1 = Oa[rowoff + lane + 64];
        float c0 = Ob[rowoff + lane], c1 = Ob[rowoff + lane + 64];
        const float ma = wsum64(a0 + a1) * (1.f/128.f);
        const float mb = wsum64(c0 + c1) * (1.f/128.f);
        a0 -= ma; a1 -= ma; c0 -= mb; c1 -= mb;
        const float vrr = wsum64(a0*a0 + a1*a1) * (1.f/128.f) + 1e-20f;
        const float vii = wsum64(c0*c0 + c1*c1) * (1.f/128.f) + 1e-20f;
        const float vri = wsum64(a0*c0 + a1*c1) * (1.f/128.f);
        const float s = sqrtf(fmaxf(vrr*vii - vri*vri, 0.f));
        const float t = sqrtf(vrr + vii + 2.f*s);
        const float inv = 1.f / (s*t);
        const float wrr = (vii + s)*inv, wii = (vrr + s)*inv, wri = -vri*inv;
        const float na0 = wrr*a0 + wri*c0, nb0 = wri*a0 + wii*c0;
        const float na1 = wrr*a1 + wri*c1, nb1 = wri*a1 + wii*c1;
        X2a[rowoff + lane]      = ra[r][lane]    + grr0*na0 + gri0*nb0 + br0;
        X2a[rowoff + lane + 64] = ra[r][lane+64] + grr1*na1 + gri1*nb1 + br1;
        X2b[rowoff + lane]      = rb[r][lane]    + gri0*na0 + gii0*nb0 + bi0;
        X2b[rowoff + lane + 64] = rb[r][lane+64] + gri1*na1 + gii1*nb1 + bi1;
    }
}

// ---------------------------------------------------------------------------
// MFMA complex linear (hi/lo bf16 split emulation of fp32):
//   Ha = A@Wr^T - B@Wi^T + br ; Hb = A@Wi^T + B@Wr^T + bi ; optional relu.
// grid (BHt*Mt/64), block 256
// ---------------------------------------------------------------------------
__global__ __launch_bounds__(256)
void k_ffn_mfma(const float* __restrict__ A, const float* __restrict__ Bm,
                const uint* __restrict__ Wrp, const uint* __restrict__ Wip,
                const float* __restrict__ br, const float* __restrict__ bi,
                float* __restrict__ Ha, float* __restrict__ Hb, int relu)
{
    const int tid = threadIdx.x;
    const size_t r0 = (size_t)blockIdx.x * 64;
    const int w = tid >> 6, l = tid & 63;
    const int l15 = l & 15, g = l >> 4;
    const size_t row = r0 + (size_t)w*16 + l15;

    f32x4 accr[8], acci[8];
    #pragma unroll
    for (int nt = 0; nt < 8; nt++) {
        accr[nt] = (f32x4){0.f, 0.f, 0.f, 0.f};
        acci[nt] = (f32x4){0.f, 0.f, 0.f, 0.f};
    }

    const float* ap = A  + row*Dd + g*8;
    const float* bp = Bm + row*Dd + g*8;
    const uint*  wr = Wrp + l15*Dd + g*8;   // + nt*2048 + cs*32
    const uint*  wi = Wip + l15*Dd + g*8;

    #pragma unroll
    for (int cs = 0; cs < 4; cs++) {
        const float4 a0 = *(const float4*)(ap + cs*32);
        const float4 a1 = *(const float4*)(ap + cs*32 + 4);
        const float4 b0 = *(const float4*)(bp + cs*32);
        const float4 b1 = *(const float4*)(bp + cs*32 + 4);
        const float av[8] = {a0.x,a0.y,a0.z,a0.w,a1.x,a1.y,a1.z,a1.w};
        const float bv[8] = {b0.x,b0.y,b0.z,b0.w,b1.x,b1.y,b1.z,b1.w};
        bf16x8 ah, al, bh_, bl_, nh, nl;
        #pragma unroll
        for (int j = 0; j < 8; j++) {
            ushort h1, l1; split2(av[j], h1, l1);
            ah[j] = (short)h1; al[j] = (short)l1;
            split2(bv[j], h1, l1);
            bh_[j] = (short)h1; bl_[j] = (short)l1;
            nh[j] = (short)(h1 ^ 0x8000);
            nl[j] = (short)(l1 ^ 0x8000);
        }
        #pragma unroll
        for (int nt = 0; nt < 8; nt++) {
            const uint* wrp2 = wr + nt*2048 + cs*32;
            const uint* wip2 = wi + nt*2048 + cs*32;
            const uint4 r0v = *(const uint4*)(wrp2);
            const uint4 r1v = *(const uint4*)(wrp2 + 4);
            const uint4 i0v = *(const uint4*)(wip2);
            const uint4 i1v = *(const uint4*)(wip2 + 4);
            bf16x8 wrh, wrl, wih, wil;
            unpack8(r0v, r1v, wrh, wrl);
            unpack8(i0v, i1v, wih, wil);
            accr[nt] = __builtin_amdgcn_mfma_f32_16x16x32_bf16(wrh, ah, accr[nt], 0, 0, 0);
            accr[nt] = __builtin_amdgcn_mfma_f32_16x16x32_bf16(wrh, al, accr[nt], 0, 0, 0);
            accr[nt] = __builtin_amdgcn_mfma_f32_16x16x32_bf16(wrl, ah, accr[nt], 0, 0, 0);
            accr[nt] = __builtin_amdgcn_mfma_f32_16x16x32_bf16(wih, nh, accr[nt], 0, 0, 0);
            accr[nt] = __builtin_amdgcn_mfma_f32_16x16x32_bf16(wih, nl, accr[nt], 0, 0, 0);
            accr[nt] = __builtin_amdgcn_mfma_f32_16x16x32_bf16(wil, nh, accr[nt], 0, 0, 0);
            acci[nt] = __builtin_amdgcn_mfma_f32_16x16x32_bf16(wih, ah, acci[nt], 0, 0, 0);
            acci[nt] = __builtin_amdgcn_mfma_f32_16x16x32_bf16(wih, al, acci[nt], 0, 0, 0);
            acci[nt] = __builtin_amdgcn_mfma_f32_16x16x32_bf16(wil, ah, acci[nt], 0, 0, 0);
            acci[nt] = __builtin_amdgcn_mfma_f32_16x16x32_bf16(wrh, bh_, acci[nt], 0, 0, 0);
            acci[nt] = __builtin_amdgcn_mfma_f32_16x16x32_bf16(wrh, bl_, acci[nt], 0, 0, 0);
            acci[nt] = __builtin_amdgcn_mfma_f32_16x16x32_bf16(wrl, bh_, acci[nt], 0, 0, 0);
        }
    }

    #pragma unroll
    for (int nt = 0; nt < 8; nt++) {
        const int n0 = nt*16 + g*4;
        const float4 vbr = *(const float4*)(br + n0);
        const float4 vbi = *(const float4*)(bi + n0);
        const float brv[4] = {vbr.x, vbr.y, vbr.z, vbr.w};
        const float biv[4] = {vbi.x, vbi.y, vbi.z, vbi.w};
        float4 orv, oiv;
        float* po = &orv.x; float* pj = &oiv.x;
        #pragma unroll
        for (int r = 0; r < 4; r++) {
            float hr = accr[nt][r] + brv[r];
            float hi = acci[nt][r] + biv[r];
            if (relu) { hr = fmaxf(hr, 0.f); hi = fmaxf(hi, 0.f); }
            po[r] = hr; pj[r] = hi;
        }
        *(float4*)(Ha + row*Dd + n0) = orv;
        *(float4*)(Hb + row*Dd + n0) = oiv;
    }
}

// ---------------------------------------------------------------------------
// Complex whitening LN (FFN branch) + residual (token-major) + transpose out
// to (B,C,M). grid (Mt/32, BHt), block 256
// ---------------------------------------------------------------------------
__global__ __launch_bounds__(256)
void k_cln_ffn(const float* __restrict__ Ha2, const float* __restrict__ Hb2,
               const float* __restrict__ X2a, const float* __restrict__ X2b,
               const float* __restrict__ Pgrr, const float* __restrict__ Pgri,
               const float* __restrict__ Pgii, const float* __restrict__ Pbr,
               const float* __restrict__ Pbi,
               float* __restrict__ OutA, float* __restrict__ OutB)
{
    __shared__ float oA[128][36];
    __shared__ float oB[128][36];
    const int tid = threadIdx.x;
    const int m0 = blockIdx.x * 32;
    const int bh = blockIdx.y;
    const int b = bh >> 1, h = bh & 1;
    const int wave = tid >> 6, lane = tid & 63;
    const float grr0 = Pgrr[lane], grr1 = Pgrr[lane+64];
    const float gri0 = Pgri[lane], gri1 = Pgri[lane+64];
    const float gii0 = Pgii[lane], gii1 = Pgii[lane+64];
    const float br0  = Pbr[lane],  br1  = Pbr[lane+64];
    const float bi0  = Pbi[lane],  bi1  = Pbi[lane+64];
    for (int r = wave; r < 32; r += 4) {
        const size_t rowoff = ((size_t)bh*Mt + m0 + r)*Dd;
        float a0 = Ha2[rowoff + lane], a1 = Ha2[rowoff + lane + 64];
        float c0 = Hb2[rowoff + lane], c1 = Hb2[rowoff + lane + 64];
        const float ma = wsum64(a0 + a1) * (1.f/128.f);
        const float mb = wsum64(c0 + c1) * (1.f/128.f);
        a0 -= ma; a1 -= ma; c0 -= mb; c1 -= mb;
        const float vrr = wsum64(a0*a0 + a1*a1) * (1.f/128.f) + 1e-20f;
        const float vii = wsum64(c0*c0 + c1*c1) * (1.f/128.f) + 1e-20f;
        const float vri = wsum64(a0*c0 + a1*c1) * (1.f/128.f);
        const float s = sqrtf(fmaxf(vrr*vii - vri*vri, 0.f));
        const float t = sqrtf(vrr + vii + 2.f*s);
        const float inv = 1.f / (s*t);
        const float wrr = (vii + s)*inv, wii = (vrr + s)*inv, wri = -vri*inv;
        const float na0 = wrr*a0 + wri*c0, nb0 = wri*a0 + wii*c0;
        const float na1 = wrr*a1 + wri*c1, nb1 = wri*a1 + wii*c1;
        oA[lane][r]    = X2a[rowoff + lane]      + grr0*na0 + gri0*nb0 + br0;
        oA[lane+64][r] = X2a[rowoff + lane + 64] + grr1*na1 + gri1*nb1 + br1;
        oB[lane][r]    = X2b[rowoff + lane]      + gri0*na0 + gii0*nb0 + bi0;
        oB[lane+64][r] = X2b[rowoff + lane + 64] + gri1*na1 + gii1*nb1 + bi1;
    }
    __syncthreads();
    const size_t obase = ((size_t)b*Cc + h*Dd)*Mt + m0;
    for (int idx = tid; idx < 1024; idx += 256) {
        const int c = idx >> 3, jq = idx & 7;
        *(float4*)(OutA + obase + (size_t)c*Mt + jq*4) = *(const float4*)&oA[c][jq*4];
        *(float4*)(OutB + obase + (size_t)c*Mt + jq*4) = *(const float4*)&oB[c][jq*4];
    }
}

// ---------------------------------------------------------------------------
extern "C" void kernel_launch(void* const* d_in, const int* in_sizes, int n_in,
                              void* d_out, int out_size, void* d_ws, size_t ws_size,
                              hipStream_t stream)
{
    const float* xA0 = (const float*)d_in[0];
    const float* xB0 = (const float*)d_in[1];
    const float* wq  = (const float*)d_in[2];
    const float* bq  = (const float*)d_in[3];
    const float* wk  = (const float*)d_in[4];
    const float* bk  = (const float*)d_in[5];
    const float* wv  = (const float*)d_in[6];
    const float* bv  = (const float*)d_in[7];
    const float* dww = (const float*)d_in[8];
    const float* dwb = (const float*)d_in[9];
    const float* lng = (const float*)d_in[10];
    const float* lnb = (const float*)d_in[11];
    const float* pw  = (const float*)d_in[12];
    const float* f1wr = (const float*)d_in[13];
    const float* f1wi = (const float*)d_in[14];
    const float* f1br = (const float*)d_in[15];
    const float* f1bi = (const float*)d_in[16];
    const float* f2wr = (const float*)d_in[17];
    const float* f2wi = (const float*)d_in[18];
    const float* f2br = (const float*)d_in[19];
    const float* f2bi = (const float*)d_in[20];
    const float* lgrr = (const float*)d_in[21];
    const float* lgri = (const float*)d_in[22];
    const float* lgii = (const float*)d_in[23];
    const float* lbr  = (const float*)d_in[24];
    const float* lbi  = (const float*)d_in[25];
    const float* rpe  = (const float*)d_in[26];

    float* ws = (float*)d_ws;
    const size_t NB = (size_t)Bz * Cc * Mt;     // 16777216 floats (64 MB)
    const size_t SC = (size_t)Bz * Cc * NSs;    // 262144 floats (1 MB)
    float* Pa  = ws;        float* Pb  = Pa  + NB;
    float* Ra  = Pb  + NB;  float* Rb  = Ra  + NB;
    float* Ya  = Rb  + NB;  float* Yb  = Ya  + SC;
    float* XsA = Yb  + SC;  float* XsB = XsA + SC;
    float* Kab = XsB + SC;  float* Kbb = Kab + SC;
    float* Vab = Kbb + SC;  float* Vbb = Vab + SC;
    float* Sp0 = Vbb + SC;  float* Sp1 = Sp0 + SC;
    float* PosA = Sp1 + SC; float* PosB = PosA + (size_t)Bz*NSs*2;
    float* Wpf  = PosB + (size_t)Bz*NSs*2;       // ffn 4*16384 + wq 65536 u32

    uint* Qs  = (uint*)Ra;           // also used as Xt (input split) early on
    uint* Ktp = (uint*)Sp0;
    uint* Vsp = (uint*)Ya;
    uint* Wp  = (uint*)Wpf;                      // ffn weights (4 x 128x128)
    uint* Wqp = Wp + (size_t)4*Dd*Dd;            // wq (256x256)

    float* outAf = (float*)d_out;
    float* outBf = outAf + NB;

    for (int l = 0; l < LAYERS; l++) {
        const float* pwq = wq + (size_t)l*Cc*Cc;
        const float* pbq = bq + (size_t)l*Cc;
        const float* pwk = wk + (size_t)l*Cc*Cc;
        const float* pbk = bk + (size_t)l*Cc;
        const float* pwv = wv + (size_t)l*Cc*Cc;
        const float* pbv = bv + (size_t)l*Cc;
        const float* pdww = dww + (size_t)l*Cc*81;
        const float* pdwb = dwb + (size_t)l*Cc;
        const float* plng = lng + (size_t)l*Cc;
        const float* plnb = lnb + (size_t)l*Cc;
        const float* ppw  = pw  + (size_t)l*2*Cc;
        const float* p1wr = f1wr + (size_t)l*Dd*Dd;
        const float* p1wi = f1wi + (size_t)l*Dd*Dd;
        const float* p1br = f1br + (size_t)l*Dd;
        const float* p1bi = f1bi + (size_t)l*Dd;
        const float* p2wr = f2wr + (size_t)l*Dd*Dd;
        const float* p2wi = f2wi + (size_t)l*Dd*Dd;
        const float* p2br = f2br + (size_t)l*Dd;
        const float* p2bi = f2bi + (size_t)l*Dd;
        const float* g0rr = lgrr + (size_t)(l*2+0)*Dd;
        const float* g0ri = lgri + (size_t)(l*2+0)*Dd;
        const float* g0ii = lgii + (size_t)(l*2+0)*Dd;
        const float* g0br = lbr  + (size_t)(l*2+0)*Dd;
        const float* g0bi = lbi  + (size_t)(l*2+0)*Dd;
        const float* g1rr = lgrr + (size_t)(l*2+1)*Dd;
        const float* g1ri = lgri + (size_t)(l*2+1)*Dd;
        const float* g1ii = lgii + (size_t)(l*2+1)*Dd;
        const float* g1br = lbr  + (size_t)(l*2+1)*Dd;
        const float* g1bi = lbi  + (size_t)(l*2+1)*Dd;
        const float* prpe = rpe + (size_t)l*NHh*RPH*RPW;

        const float* inA = l ? outAf : xA0;
        const float* inB = l ? outBf : xB0;

        // weight packing for this layer (independent of everything else)
        dim3 gW(64, 4);
        k_wsplit4<<<gW, 256, 0, stream>>>(p1wr, p1wi, p2wr, p2wi, Wp);
        k_wsplit1<<<256, 256, 0, stream>>>(pwq, Wqp);

        // input split (token-major packed) -> Xt in Ra/Rb region
        dim3 gQs(Mt/64, BHt);
        k_qsplit<<<gQs, 256, 0, stream>>>(inA, inB, Qs);   // Qs == Xt here

        // Q projection via MFMA (LDS-staged W): Xt x Wq -> Pa/Pb ([c][m] f32)
        dim3 gPQ(Mt/64, Bz);
        k_projq_mfma<<<gPQ, 256, 0, stream>>>(Qs, Wqp, pbq, Pa, 0);
        k_projq_mfma<<<gPQ, 256, 0, stream>>>(Qs, Wqp, pbq, Pb, 1);

        dim3 gD(Cc, Bz);
        k_dwconv<<<gD, 256, 0, stream>>>(Pa, pdww, pdwb, Ya);
        k_dwconv<<<gD, 256, 0, stream>>>(Pb, pdww, pdwb, Yb);

        dim3 gL(NSs, Bz);
        k_lnpw<<<gL, 256, 0, stream>>>(Ya, plng, plnb, ppw, PosA);
        k_lnpw<<<gL, 256, 0, stream>>>(Yb, plng, plnb, ppw, PosB);

        dim3 gS(Cc, Bz);
        k_gsample<<<gS, 256, 0, stream>>>(inA, PosA, XsA);
        k_gsample<<<gS, 256, 0, stream>>>(inB, PosB, XsB);

        dim3 gKV(NSs/64, Cc/64, Bz);
        k_proj<<<gKV, 256, 0, stream>>>(XsA, pwk, pbk, Kab, NSs);
        k_proj<<<gKV, 256, 0, stream>>>(XsB, pwk, pbk, Kbb, NSs);
        k_proj<<<gKV, 256, 0, stream>>>(XsA, pwv, pbv, Vab, NSs);
        k_proj<<<gKV, 256, 0, stream>>>(XsB, pwv, pbv, Vbb, NSs);

        // packed bf16-pair pre-splits (Ya/Yb dead after k_lnpw)
        dim3 gKs(NSs/64, BHt);
        k_ksplit<<<gKs, 256, 0, stream>>>(Kab, Kbb, Ktp);
        k_vsplit<<<2048, 256, 0, stream>>>(Vab, Vbb, Vsp);
        // Q split (overwrites Xt -- dead after projq)
        k_qsplit<<<gQs, 256, 0, stream>>>(Pa, Pb, Qs);

        // attn: Qs(R) -> O(P).  Qs dead afterwards.
        dim3 gA(Mt/64, BHt);
        k_attn_mfma<<<gA, 256, 0, stream>>>(Qs, Ktp, Vsp, PosA, prpe, Pa, Pb);

        // cln_attn: O(P) + X(in) -> X2(R).
        dim3 gC(Mt/32, BHt);
        k_cln_attn<<<gC, 256, 0, stream>>>(Pa, Pb, inA, inB,
                                           g0rr, g0ri, g0ii, g0br, g0bi, Ra, Rb);

        // fc1: X2(R) -> H1(P); fc2: H1(P) -> H2(P) in-place.  (MFMA hi/lo)
        dim3 gF((unsigned)((size_t)BHt*Mt/64));
        k_ffn_mfma<<<gF, 256, 0, stream>>>(Ra, Rb, Wp, Wp + (size_t)Dd*Dd,
                                           p1br, p1bi, Pa, Pb, 1);
        k_ffn_mfma<<<gF, 256, 0, stream>>>(Pa, Pb, Wp + (size_t)2*Dd*Dd,
                                           Wp + (size_t)3*Dd*Dd,
                                           p2br, p2bi, Pa, Pb, 0);

        // cln_ffn: H2(P) + X2(R) -> layer output
        k_cln_ffn<<<gC, 256, 0, stream>>>(Pa, Pb, Ra, Rb,
                                          g1rr, g1ri, g1ii, g1br, g1bi, outAf, outBf);
    }
    (void)in_sizes; (void)n_in; (void)out_size; (void)ws_size;
}

// Round 10
// 2412.159 us; speedup vs baseline: 1.1875x; 1.0605x over previous
//
#include <hip/hip_runtime.h>
#include <math.h>

#define DEVFN static __device__ __forceinline__

constexpr int LAYERS = 2;
constexpr int Bz = 4;
constexpr int Cc = 256;
constexpr int Hh = 128;
constexpr int Ww = 128;
constexpr int Dd = 128;
constexpr int NHh = 2;
constexpr int BHt = Bz * NHh;              // 8
constexpr int Mt  = Hh * Ww;               // 16384
constexpr int HK = 16, WK = 16;
constexpr int NSs = HK * WK;               // 256
constexpr int STR = 8, PADc = 4;
constexpr int RPH = 2*Hh - 1, RPW = 2*Ww - 1;  // 255
constexpr float SCALE_F = 0.17677669529663687f; // 32^-0.5

typedef __attribute__((ext_vector_type(8))) short  bf16x8;
typedef __attribute__((ext_vector_type(4))) float  f32x4;

DEVFN float wsum64(float v) {
    #pragma unroll
    for (int off = 32; off > 0; off >>= 1) v += __shfl_xor(v, off, 64);
    return v;
}

// fp32 -> bf16 hi + bf16 lo (RNE both); x ~= hi + lo with ~2^-17 rel error.
DEVFN void split2(float x, ushort& h, ushort& l)
{
    const uint u  = __float_as_uint(x);
    const uint hb = (u + 0x7fffu + ((u >> 16) & 1u)) & 0xffff0000u;
    h = (ushort)(hb >> 16);
    const float r = x - __uint_as_float(hb);
    const uint ul = __float_as_uint(r);
    l = (ushort)((ul + 0x7fffu + ((ul >> 16) & 1u)) >> 16);
}

DEVFN ushort f2bf(float x)
{
    const uint u = __float_as_uint(x);
    return (ushort)((u + 0x7fffu + ((u >> 16) & 1u)) >> 16);
}
DEVFN float bf2f(ushort s) { return __uint_as_float(((uint)s) << 16); }

DEVFN uint shfu(uint v, int src) { return (uint)__shfl((int)v, src, 64); }

DEVFN bf16x8 pack4(uint a, uint b, uint c, uint d)
{
    union { uint u[4]; bf16x8 v; } t;
    t.u[0] = a; t.u[1] = b; t.u[2] = c; t.u[3] = d;
    return t.v;
}

// unpack 8 packed words (hi<<16|lo) into hi/lo bf16x8 fragments
DEVFN void unpack8(uint4 a, uint4 b, bf16x8& h, bf16x8& l)
{
    const uint u[8] = {a.x, a.y, a.z, a.w, b.x, b.y, b.z, b.w};
    #pragma unroll
    for (int j = 0; j < 8; j++) {
        h[j] = (short)(u[j] >> 16);
        l[j] = (short)(u[j] & 0xffffu);
    }
}

// ---------------------------------------------------------------------------
// Generic 1x1-conv projection (fp32 VALU): used only for the small K/V
// projections (Mdim = NSs = 256).
// grid (Mdim/64, Cc/64, Bz), block 256
// ---------------------------------------------------------------------------
__global__ __launch_bounds__(256)
void k_proj(const float* __restrict__ X, const float* __restrict__ W,
            const float* __restrict__ bias, float* __restrict__ Out, int Mdim)
{
    __shared__ float wsm[16][64];
    __shared__ float xsm[16][64];
    const int tid = threadIdx.x;
    const int m0 = blockIdx.x * 64;
    const int o0 = blockIdx.y * 64;
    const float* Xb = X + (size_t)blockIdx.z * Cc * Mdim;
    float* Ob = Out + (size_t)blockIdx.z * Cc * Mdim;
    const int to = tid >> 4;   // 0..15 (o sub /4)
    const int tm = tid & 15;   // 0..15 (m sub /4)
    float acc[4][4] = {{0.f}};
    for (int k0 = 0; k0 < Cc; k0 += 16) {
        {
            const int i = tid >> 2, kq = tid & 3;
            float4 w4 = *(const float4*)(W + (size_t)(o0 + i)*Cc + k0 + kq*4);
            wsm[kq*4+0][i] = w4.x; wsm[kq*4+1][i] = w4.y;
            wsm[kq*4+2][i] = w4.z; wsm[kq*4+3][i] = w4.w;
            const int kk = tid >> 4, jq = tid & 15;
            *(float4*)&xsm[kk][jq*4] =
                *(const float4*)(Xb + (size_t)(k0 + kk)*Mdim + m0 + jq*4);
        }
        __syncthreads();
        #pragma unroll
        for (int kk = 0; kk < 16; kk++) {
            float4 a4 = *(const float4*)&wsm[kk][to*4];
            float4 b4 = *(const float4*)&xsm[kk][tm*4];
            float av[4] = {a4.x, a4.y, a4.z, a4.w};
            float bv[4] = {b4.x, b4.y, b4.z, b4.w};
            #pragma unroll
            for (int ii = 0; ii < 4; ii++)
                #pragma unroll
                for (int jj = 0; jj < 4; jj++)
                    acc[ii][jj] += av[ii] * bv[jj];
        }
        __syncthreads();
    }
    #pragma unroll
    for (int ii = 0; ii < 4; ii++) {
        const int o = o0 + to*4 + ii;
        const float bo = bias[o];
        float4 r4 = make_float4(acc[ii][0]+bo, acc[ii][1]+bo, acc[ii][2]+bo, acc[ii][3]+bo);
        *(float4*)(Ob + (size_t)o*Mdim + m0 + tm*4) = r4;
    }
}

// ---------------------------------------------------------------------------
// MFMA 1x1-conv projection for the big Q GEMM (hi/lo bf16 split), v2:
// LDS-staged weights.  (validated round 9; unchanged this round)
// grid (Mt/64, Bz), block 256
// ---------------------------------------------------------------------------
__global__ __launch_bounds__(256, 2)
void k_projq_mfma(const uint* __restrict__ Xt, const uint* __restrict__ Wqp,
                  const float* __restrict__ bias, float* __restrict__ Out,
                  int s)
{
    __shared__ __align__(16) char smem[256 * 68 * 4];   // 69632 B (union)
    char* const kv0 = smem;                  // staging dbuf: 2 x 16KB
    char* const kv1 = smem + 16384;
    float* const ot = (float*)smem;          // epilogue transpose (69632 B)
    const int tid = threadIdx.x;
    const int m0 = blockIdx.x * 64;
    const int b  = blockIdx.y;
    const int w = tid >> 6, l = tid & 63;
    const int l15 = l & 15, g = l >> 4;
    const int m = m0 + w*16 + l15;

    auto stage = [&](int p, const uint* chunk) {
        char* dst = p ? kv1 : kv0;
        #pragma unroll
        for (int r = 0; r < 4; r++) {
            const int idx = r*1024 + tid*4;              // u32 index in chunk
            const uint4 v = *(const uint4*)(chunk + idx);
            const int byte = idx << 2;
            const int swz = ((byte >> 10) & 7) << 4;
            *(uint4*)(dst + (byte ^ swz)) = v;
        }
    };

    // ---- B fragments: X token column m, channels c = cs*32 + g*8 + j
    bf16x8 xh[8], xl[8];
    {
        const uint* xp0 = Xt + ((size_t)(b*2 + 0)*Mt + m)*256 + s*128 + g*8;
        const uint* xp1 = Xt + ((size_t)(b*2 + 1)*Mt + m)*256 + s*128 + g*8;
        #pragma unroll
        for (int cs = 0; cs < 8; cs++) {
            const uint* xp = ((cs < 4) ? xp0 : xp1) + (cs & 3)*32;
            const uint4 x0 = *(const uint4*)(xp);
            const uint4 x1 = *(const uint4*)(xp + 4);
            unpack8(x0, x1, xh[cs], xl[cs]);
        }
    }

    // ---- MFMA with staged W: acc[nt] holds Out[o = nt*16 + g*4 + r][m]
    f32x4 acc[16];
    #pragma unroll
    for (int nt = 0; nt < 16; nt++) acc[nt] = (f32x4){0.f, 0.f, 0.f, 0.f};

    const int rowb = l15 << 10;
    const int sw = (l15 & 7) << 4;

    stage(0, Wqp);
    __syncthreads();                       // chunk 0 ready
    #pragma unroll
    for (int nt = 0; nt < 16; nt++) {
        if (nt < 15) stage((nt + 1) & 1, Wqp + (nt + 1)*4096);
        const char* bufc = (nt & 1) ? kv1 : kv0;
        #pragma unroll
        for (int cs = 0; cs < 8; cs++) {
            const int a0 = rowb + cs*128 + g*32;
            const uint4 w0 = *(const uint4*)(bufc + (a0 ^ sw));
            const uint4 w1 = *(const uint4*)(bufc + ((a0 + 16) ^ sw));
            bf16x8 wh, wl; unpack8(w0, w1, wh, wl);
            acc[nt] = __builtin_amdgcn_mfma_f32_16x16x32_bf16(wh, xh[cs], acc[nt], 0, 0, 0);
            acc[nt] = __builtin_amdgcn_mfma_f32_16x16x32_bf16(wh, xl[cs], acc[nt], 0, 0, 0);
            acc[nt] = __builtin_amdgcn_mfma_f32_16x16x32_bf16(wl, xh[cs], acc[nt], 0, 0, 0);
        }
        __syncthreads();                   // next chunk landed; buf free
    }

    // ---- epilogue: bias, LDS transpose, coalesced [o][m] stores
    #pragma unroll
    for (int nt = 0; nt < 16; nt++) {
        #pragma unroll
        for (int r = 0; r < 4; r++) {
            const int o = nt*16 + g*4 + r;
            ot[o*68 + w*16 + l15] = acc[nt][r] + bias[o];
        }
    }
    __syncthreads();
    #pragma unroll
    for (int it = 0; it < 16; it++) {
        const int idx = it*256 + tid;      // 0..4095 float4s
        const int o = idx >> 4, mq = idx & 15;
        const float4 v = *(const float4*)&ot[o*68 + mq*4];
        *(float4*)(Out + ((size_t)b*Cc + o)*Mt + m0 + mq*4) = v;
    }
}

// ---------------------------------------------------------------------------
// Depthwise 9x9 stride-8 pad-4 conv: Y[b,c,i,j], grid (Cc, Bz), block 256
// ---------------------------------------------------------------------------
__global__ __launch_bounds__(256)
void k_dwconv(const float* __restrict__ Q, const float* __restrict__ Wdw,
              const float* __restrict__ Bdw, float* __restrict__ Y)
{
    const int c = blockIdx.x, b = blockIdx.y;
    __shared__ float wsmem[81];
    const int tid = threadIdx.x;
    if (tid < 81) wsmem[tid] = Wdw[c*81 + tid];
    __syncthreads();
    const int i = tid >> 4, j = tid & 15;
    const float* Qc = Q + ((size_t)b*Cc + c)*Mt;
    float acc = Bdw[c];
    const int ybase = i*STR - PADc, xbase = j*STR - PADc;
    #pragma unroll
    for (int u = 0; u < 9; u++) {
        const int y = ybase + u;
        if (y < 0 || y >= Hh) continue;
        #pragma unroll
        for (int v = 0; v < 9; v++) {
            const int x = xbase + v;
            if (x < 0 || x >= Ww) continue;
            acc += wsmem[u*9+v] * Qc[y*Ww + x];
        }
    }
    Y[((size_t)b*Cc + c)*NSs + i*WK + j] = acc;
}

// ---------------------------------------------------------------------------
// Channel-LN + exact GELU + pointwise(2) + ref grid -> Pos[b,s,2]
// grid (NSs, Bz), block 256 (tid = channel)
// ---------------------------------------------------------------------------
DEVFN float block_reduce(float v, float* red, int tid)
{
    red[tid] = v; __syncthreads();
    #pragma unroll
    for (int s2 = 128; s2 > 0; s2 >>= 1) {
        if (tid < s2) red[tid] += red[tid + s2];
        __syncthreads();
    }
    const float r = red[0];
    __syncthreads();
    return r;
}

__global__ __launch_bounds__(256)
void k_lnpw(const float* __restrict__ Y, const float* __restrict__ G,
            const float* __restrict__ Bt, const float* __restrict__ PW,
            float* __restrict__ Pos)
{
    __shared__ float red[256];
    const int ij = blockIdx.x, b = blockIdx.y;
    const int tid = threadIdx.x;
    const float y = Y[((size_t)b*Cc + tid)*NSs + ij];
    const float m = block_reduce(y, red, tid) * (1.f/256.f);
    const float d = y - m;
    const float v = block_reduce(d*d, red, tid) * (1.f/256.f);
    const float g = d * rsqrtf(v + 1e-5f) * G[tid] + Bt[tid];
    const float ge = 0.5f * g * (1.f + erff(g * 0.70710678118654752f));
    const float off0 = block_reduce(ge * PW[tid], red, tid);
    const float off1 = block_reduce(ge * PW[Cc + tid], red, tid);
    if (tid == 0) {
        const int i = ij >> 4, j = ij & 15;
        const float refy = ((float)i + 0.5f) * (2.f/15.f) - 1.f;
        const float refx = ((float)j + 0.5f) * (2.f/15.f) - 1.f;
        Pos[((size_t)b*NSs + ij)*2 + 0] = off0 + refy;
        Pos[((size_t)b*NSs + ij)*2 + 1] = off1 + refx;
    }
}

// ---------------------------------------------------------------------------
// Bilinear grid sample (zero padding): Xs[b,c,s] = bilerp(X[b,c], Pos[b,s])
// grid (Cc, Bz), block 256 (tid = sample index s)
// ---------------------------------------------------------------------------
__global__ __launch_bounds__(256)
void k_gsample(const float* __restrict__ X, const float* __restrict__ Pos,
               float* __restrict__ Xs)
{
    const int c = blockIdx.x, b = blockIdx.y, s = threadIdx.x;
    const float py = Pos[((size_t)b*NSs + s)*2 + 0];
    const float px = Pos[((size_t)b*NSs + s)*2 + 1];
    const float x = (px + 1.f) * 0.5f * (float)(Ww - 1);
    const float y = (py + 1.f) * 0.5f * (float)(Hh - 1);
    const float x0 = floorf(x), y0 = floorf(y);
    const float wx1 = x - x0, wx0 = 1.f - wx1;
    const float wy1 = y - y0, wy0 = 1.f - wy1;
    const float* Xc = X + ((size_t)b*Cc + c)*Mt;
    float acc = 0.f;
    #pragma unroll
    for (int t = 0; t < 4; t++) {
        const float xx = x0 + (float)(t & 1);
        const float yy = y0 + (float)(t >> 1);
        float w = ((t & 1) ? wx1 : wx0) * ((t >> 1) ? wy1 : wy0);
        const bool valid = (xx >= 0.f) && (xx <= (float)(Ww-1)) &&
                           (yy >= 0.f) && (yy <= (float)(Hh-1));
        const int xi = (int)fminf(fmaxf(xx, 0.f), (float)(Ww-1));
        const int yi = (int)fminf(fmaxf(yy, 0.f), (float)(Hh-1));
        acc += (valid ? w : 0.f) * Xc[yi*Ww + xi];
    }
    Xs[((size_t)b*Cc + c)*NSs + s] = acc;
}

// ---------------------------------------------------------------------------
// Split+transpose pre-pass: pair of fp32 [b][c][m] -> packed u32 (hi<<16|lo)
// Out[bh][m][cc2], cc2 = stream-a ch 0..127, stream-b ch 128..255.
// Used for both the layer input (Xt) and the computed Q (Qs).
// grid (Mt/64, BHt), block 256
// ---------------------------------------------------------------------------
__global__ __launch_bounds__(256)
void k_qsplit(const float* __restrict__ Qa, const float* __restrict__ Qb,
              uint* __restrict__ Qs)
{
    __shared__ float tile[64][65];
    const int tid = threadIdx.x;
    const int m0 = blockIdx.x * 64;
    const int bh = blockIdx.y;
    const int b = bh >> 1, h = bh & 1;
    for (int ccblk = 0; ccblk < 4; ccblk++) {
        #pragma unroll
        for (int i = 0; i < 4; i++) {
            const int idx = i*256 + tid;           // 0..1023
            const int ccl = idx >> 4, mq = idx & 15;
            const int cc2 = ccblk*64 + ccl;
            const float* src = (cc2 >> 7) ? Qb : Qa;
            *(float4*)&tile[ccl][mq*4] =
                *(const float4*)(src + ((size_t)b*Cc + h*Dd + (cc2 & 127))*Mt + m0 + mq*4);
        }
        __syncthreads();
        #pragma unroll
        for (int i = 0; i < 16; i++) {
            const int idx = i*256 + tid;
            const int ml = idx >> 6, ccl = idx & 63;
            ushort hi, lo; split2(tile[ccl][ml], hi, lo);
            Qs[((size_t)bh*Mt + m0 + ml)*256 + ccblk*64 + ccl] = ((uint)hi << 16) | lo;
        }
        __syncthreads();
    }
}

// ---------------------------------------------------------------------------
// K split+transpose pre-pass, PLANE layout: K fp32 [b][c][n] ->
// KtpH/KtpL bf16 ushort planes [bh][n][cc2] (MFMA-ready, no unpack needed).
// grid (NSs/64, BHt), block 256
// ---------------------------------------------------------------------------
__global__ __launch_bounds__(256)
void k_ksplit(const float* __restrict__ Ka, const float* __restrict__ Kb,
              ushort* __restrict__ KtpH, ushort* __restrict__ KtpL)
{
    __shared__ float tile[64][65];
    const int tid = threadIdx.x;
    const int n0 = blockIdx.x * 64;
    const int bh = blockIdx.y;
    const int b = bh >> 1, h = bh & 1;
    for (int ccblk = 0; ccblk < 4; ccblk++) {
        #pragma unroll
        for (int i = 0; i < 16; i++) {
            const int idx = i*256 + tid;
            const int ccl = idx >> 6, nl = idx & 63;
            const int cc2 = ccblk*64 + ccl;
            const float* src = (cc2 >> 7) ? Kb : Ka;
            tile[ccl][nl] = src[((size_t)b*Cc + h*Dd + (cc2 & 127))*NSs + n0 + nl];
        }
        __syncthreads();
        #pragma unroll
        for (int i = 0; i < 8; i++) {
            const int idx = i*256 + tid;           // 0..2047
            const int nl = idx >> 5, cp = idx & 31;
            const int ccl = cp*2;
            ushort h0, l0, h1, l1;
            split2(tile[ccl][nl],     h0, l0);
            split2(tile[ccl + 1][nl], h1, l1);
            const size_t o = ((size_t)bh*NSs + n0 + nl)*256 + ccblk*64 + ccl;
            *(uint*)&KtpH[o] = (uint)h0 | ((uint)h1 << 16);
            *(uint*)&KtpL[o] = (uint)l0 | ((uint)l1 << 16);
        }
        __syncthreads();
    }
}

// ---------------------------------------------------------------------------
// V split pre-pass, PLANE layout: V fp32 [b][c][n] -> VsH/VsL ushort planes
// [bh][j][n].  grid (1024), block 256 (2 adjacent n per thread).
// ---------------------------------------------------------------------------
__global__ __launch_bounds__(256)
void k_vsplit(const float* __restrict__ Va, const float* __restrict__ Vb,
              ushort* __restrict__ VsH, ushort* __restrict__ VsL)
{
    const size_t e = ((size_t)blockIdx.x*256 + threadIdx.x) * 2;
    const int n  = (int)(e & 255);
    const int j  = (int)((e >> 8) & 255);
    const int bh = (int)(e >> 16);
    const int b = bh >> 1, h = bh & 1;
    const float* src = (j >> 7) ? Vb : Va;
    const float* p = src + ((size_t)b*Cc + h*Dd + (j & 127))*NSs + n;
    ushort h0, l0, h1, l1;
    split2(p[0], h0, l0);
    split2(p[1], h1, l1);
    *(uint*)&VsH[e] = (uint)h0 | ((uint)h1 << 16);
    *(uint*)&VsL[e] = (uint)l0 | ((uint)l1 << 16);
}

// ---------------------------------------------------------------------------
// FFN weight pack pre-pass: 4 matrices (128x128, row-major [o][k]) -> packed
// u32 (hi<<16|lo).  grid (64, 4), block 256.
// ---------------------------------------------------------------------------
__global__ __launch_bounds__(256)
void k_wsplit4(const float* __restrict__ W0, const float* __restrict__ W1,
               const float* __restrict__ W2, const float* __restrict__ W3,
               uint* __restrict__ Wp)
{
    const int mat = blockIdx.y;
    const float* W = (mat == 0) ? W0 : (mat == 1) ? W1 : (mat == 2) ? W2 : W3;
    const int i = blockIdx.x*256 + threadIdx.x;   // 0..16383
    ushort hi, lo; split2(W[i], hi, lo);
    Wp[(size_t)mat*Dd*Dd + i] = ((uint)hi << 16) | lo;
}

// ---------------------------------------------------------------------------
// Single 256x256 weight pack (wq): grid (256), block 256.
// ---------------------------------------------------------------------------
__global__ __launch_bounds__(256)
void k_wsplit1(const float* __restrict__ W, uint* __restrict__ Wp)
{
    const int i = blockIdx.x*256 + threadIdx.x;   // 0..65535
    ushort hi, lo; split2(W[i], hi, lo);
    Wp[i] = ((uint)hi << 16) | lo;
}

// ---------------------------------------------------------------------------
// MFMA attention v5: plane-separated K/V (zero inner-loop unpack VALU).
// K/V stored as hi/lo bf16 planes; stage() copies 8KB hi + 8KB lo per chunk
// into a 2x16KB LDS double buffer (swizzled); fragment reads are direct
// MFMA-ready bf16x8 ds_reads.  Identical MFMA order -> bit-identical output.
// grid (Mt/64, BHt), block 256
// ---------------------------------------------------------------------------
__global__ __launch_bounds__(256, 2)
void k_attn_mfma(const uint* __restrict__ Qs,
                 const ushort* __restrict__ KtpH, const ushort* __restrict__ KtpL,
                 const ushort* __restrict__ VsH,  const ushort* __restrict__ VsL,
                 const float* __restrict__ Pos, const float* __restrict__ Rpe,
                 float* __restrict__ Oa, float* __restrict__ Ob)
{
    constexpr int GS = 66;                 // 65 entries + 1 pad
    __shared__ ushort Gt[NSs * GS];        // 33792 B (bf16)
    __shared__ float fxs[NSs];             // 1024 B
    __shared__ __align__(16) char kvbuf[2][16384];  // 2 x (8KB hi + 8KB lo)
    const int tid = threadIdx.x;
    const int m0 = blockIdx.x * 64;
    const int bh = blockIdx.y;
    const int b = bh >> 1, h = bh & 1;
    const int j0 = m0 & 127;               // jq base for this block
    const int iq = m0 >> 7;                // constant over the block
    const float* Rh = Rpe + (size_t)h * RPH * RPW;

    // ---- G-table build: thread n handles sample n (contiguous row reads)
    {
        const int n = tid;
        const float py = Pos[((size_t)b*NSs + n)*2 + 0];
        const float px = Pos[((size_t)b*NSs + n)*2 + 1];
        const float xf = (float)j0 + 63.5f - 63.5f*px;   // x(m) = xf + dm
        const float yf = (float)iq + 63.5f - 63.5f*py;   // y const over block
        const float xbf = floorf(xf), ybf = floorf(yf);
        const float fx = xf - xbf, fy = yf - ybf;
        fxs[n] = fx;
        const int yb = (int)ybf;
        const float wy0 = (1.f - fy) * ((yb   >= 0 && yb   <= RPH-1) ? 1.f : 0.f);
        const float wy1 = fy         * ((yb+1 >= 0 && yb+1 <= RPH-1) ? 1.f : 0.f);
        const int y0c = yb   < 0 ? 0 : (yb   > RPH-1 ? RPH-1 : yb);
        const int y1c = yb+1 < 0 ? 0 : (yb+1 > RPH-1 ? RPH-1 : yb+1);
        const float* r0 = Rh + (size_t)y0c * RPW;
        const float* r1 = Rh + (size_t)y1c * RPW;
        const int xb = (int)xbf;
        #pragma unroll 4
        for (int t = 0; t <= 64; t++) {
            const int xi = xb + t;
            const int xc = xi < 0 ? 0 : (xi > RPW-1 ? RPW-1 : xi);
            const float v = wy0*r0[xc] + wy1*r1[xc];
            Gt[n*GS + t] = f2bf((xi >= 0 && xi <= RPW-1) ? v : 0.f);
        }
    }

    const int w = tid >> 6, l = tid & 63;
    const int l15 = l & 15, g = l >> 4;
    const int mcol = m0 + w*16 + l15;      // this lane's output column m

    // staging: one chunk = 16 rows; hi 8KB + lo 8KB, both swizzled by row.
    const ushort* kbaseH = KtpH + (size_t)bh * 65536;
    const ushort* kbaseL = KtpL + (size_t)bh * 65536;
    const ushort* vbaseH = VsH  + (size_t)bh * 65536;
    const ushort* vbaseL = VsL  + (size_t)bh * 65536;
    char* const kv0 = kvbuf[0];
    char* const kv1 = kvbuf[1];
    auto stage = [&](int p, const ushort* hs, const ushort* ls) {
        char* dst = p ? kv1 : kv0;
        #pragma unroll
        for (int r = 0; r < 2; r++) {
            const int byte = r*4096 + tid*16;
            const int swz = ((byte >> 9) & 7) << 4;
            *(uint4*)(dst + (byte ^ swz)) =
                *(const uint4*)((const char*)hs + byte);
            *(uint4*)(dst + 8192 + (byte ^ swz)) =
                *(const uint4*)((const char*)ls + byte);
        }
    };

    // ---- Q fragments -> registers, unpacked once (64 VGPR)
    bf16x8 qh[8], ql[8];
    {
        const uint* qp = Qs + ((size_t)bh*Mt + mcol)*256 + g*8;
        #pragma unroll
        for (int cs = 0; cs < 8; cs++) {
            const uint4 q0 = *(const uint4*)(qp + cs*32);
            const uint4 q1 = *(const uint4*)(qp + cs*32 + 4);
            unpack8(q0, q1, qh[cs], ql[cs]);
        }
    }

    // ---- QK^T with staged K: acc[nt] = S[n = nt*16+g*4+r][m = mcol]
    f32x4 acc[16];
    #pragma unroll
    for (int nt = 0; nt < 16; nt++) acc[nt] = (f32x4){0.f, 0.f, 0.f, 0.f};

    const int rowb = l15 << 9;             // 512B plane rows
    const int sw = (l15 & 7) << 4;

    stage(0, kbaseH, kbaseL);
    __syncthreads();                       // chunk 0 ready (+ Gt/fxs ready)
    #pragma unroll
    for (int nt = 0; nt < 16; nt++) {
        if (nt < 15) stage((nt + 1) & 1,
                           kbaseH + (nt + 1)*4096, kbaseL + (nt + 1)*4096);
        const char* bufc = (nt & 1) ? kv1 : kv0;
        #pragma unroll
        for (int cs = 0; cs < 8; cs++) {
            const int a0 = rowb + cs*64 + g*16;
            const bf16x8 kh = *(const bf16x8*)(bufc + (a0 ^ sw));
            const bf16x8 kl = *(const bf16x8*)(bufc + 8192 + (a0 ^ sw));
            acc[nt] = __builtin_amdgcn_mfma_f32_16x16x32_bf16(kh, qh[cs], acc[nt], 0, 0, 0);
            acc[nt] = __builtin_amdgcn_mfma_f32_16x16x32_bf16(kh, ql[cs], acc[nt], 0, 0, 0);
            acc[nt] = __builtin_amdgcn_mfma_f32_16x16x32_bf16(kl, qh[cs], acc[nt], 0, 0, 0);
        }
        __syncthreads();                   // next chunk landed; buf free
    }

    // ---- bias + softmax (row m is wave-local across the 4 g-lanes)
    const int dm = w*16 + l15;
    float mx = -1e30f;
    #pragma unroll
    for (int nt = 0; nt < 16; nt++) {
        #pragma unroll
        for (int r = 0; r < 4; r++) {
            const int n = nt*16 + g*4 + r;
            const float g0 = bf2f(Gt[n*GS + dm]);
            const float g1 = bf2f(Gt[n*GS + dm + 1]);
            const float bias = g0 + fxs[n]*(g1 - g0);
            const float s = SCALE_F*acc[nt][r] + bias;
            acc[nt][r] = s;
            mx = fmaxf(mx, s);
        }
    }
    mx = fmaxf(mx, __shfl_xor(mx, 16, 64));
    mx = fmaxf(mx, __shfl_xor(mx, 32, 64));
    float sum = 0.f;
    #pragma unroll
    for (int nt = 0; nt < 16; nt++)
        #pragma unroll
        for (int r = 0; r < 4; r++) {
            const float e = __expf(acc[nt][r] - mx);
            acc[nt][r] = e;
            sum += e;
        }
    sum += __shfl_xor(sum, 16, 64);
    sum += __shfl_xor(sum, 32, 64);
    const float inv = 1.f / sum;

    // ---- pack P to bf16 hi/lo word pairs (per nt: words [r0|r1], [r2|r3])
    uint hU0[16], hU1[16], lU0[16], lU1[16];
    #pragma unroll
    for (int nt = 0; nt < 16; nt++) {
        ushort ph_[4], pl_[4];
        #pragma unroll
        for (int r = 0; r < 4; r++) split2(acc[nt][r] * inv, ph_[r], pl_[r]);
        hU0[nt] = (uint)ph_[0] | ((uint)ph_[1] << 16);
        hU1[nt] = (uint)ph_[2] | ((uint)ph_[3] << 16);
        lU0[nt] = (uint)pl_[0] | ((uint)pl_[1] << 16);
        lU1[nt] = (uint)pl_[2] | ((uint)pl_[3] << 16);
    }

    // ---- shuffle-precompute PV A-fragments (identical across jt)
    const int srcA = (((2*g)     & 3) << 4) | l15;
    const int srcB = (((2*g + 1) & 3) << 4) | l15;
    const bool hi2 = (g >> 1) & 1;
    bf16x8 ph[8], pl[8];
    #pragma unroll
    for (int cs = 0; cs < 8; cs++) {
        uint A00 = shfu(hU0[2*cs], srcA), A01 = shfu(hU0[2*cs+1], srcA);
        uint A10 = shfu(hU1[2*cs], srcA), A11 = shfu(hU1[2*cs+1], srcA);
        uint B00 = shfu(hU0[2*cs], srcB), B01 = shfu(hU0[2*cs+1], srcB);
        uint B10 = shfu(hU1[2*cs], srcB), B11 = shfu(hU1[2*cs+1], srcB);
        ph[cs] = pack4(hi2 ? A01 : A00, hi2 ? A11 : A10,
                       hi2 ? B01 : B00, hi2 ? B11 : B10);
        A00 = shfu(lU0[2*cs], srcA); A01 = shfu(lU0[2*cs+1], srcA);
        A10 = shfu(lU1[2*cs], srcA); A11 = shfu(lU1[2*cs+1], srcA);
        B00 = shfu(lU0[2*cs], srcB); B01 = shfu(lU0[2*cs+1], srcB);
        B10 = shfu(lU1[2*cs], srcB); B11 = shfu(lU1[2*cs+1], srcB);
        pl[cs] = pack4(hi2 ? A01 : A00, hi2 ? A11 : A10,
                       hi2 ? B01 : B00, hi2 ? B11 : B10);
    }

    // ---- PV with staged V, jt-outer (per-jt f32x4 accumulator)
    const size_t rowbase = ((size_t)bh*Mt + mcol)*Dd;
    stage(0, vbaseH, vbaseL);              // kvbuf[0] free: QK done (barrier)
    __syncthreads();
    for (int jt = 0; jt < 16; jt++) {
        if (jt < 15) stage((jt + 1) & 1,
                           vbaseH + (jt + 1)*4096, vbaseL + (jt + 1)*4096);
        const char* bufc = (jt & 1) ? kv1 : kv0;
        f32x4 a2 = (f32x4){0.f, 0.f, 0.f, 0.f};
        #pragma unroll
        for (int cs = 0; cs < 8; cs++) {
            const int a0 = rowb + cs*64 + g*16;
            const bf16x8 vh = *(const bf16x8*)(bufc + (a0 ^ sw));
            const bf16x8 vl = *(const bf16x8*)(bufc + 8192 + (a0 ^ sw));
            a2 = __builtin_amdgcn_mfma_f32_16x16x32_bf16(vh, ph[cs], a2, 0, 0, 0);
            a2 = __builtin_amdgcn_mfma_f32_16x16x32_bf16(vh, pl[cs], a2, 0, 0, 0);
            a2 = __builtin_amdgcn_mfma_f32_16x16x32_bf16(vl, ph[cs], a2, 0, 0, 0);
        }
        const float4 o = make_float4(a2[0], a2[1], a2[2], a2[3]);
        const int jv0 = jt*16 + g*4;
        if (jt < 8) *(float4*)(Oa + rowbase + jv0) = o;
        else        *(float4*)(Ob + rowbase + jv0 - 128) = o;
        __syncthreads();
    }
}

// ---------------------------------------------------------------------------
// Complex whitening LN (attention branch) + residual from (B,C,M) input.
// grid (Mt/32, BHt), block 256. X2 written token-major.
// ---------------------------------------------------------------------------
__global__ __launch_bounds__(256)
void k_cln_attn(const float* __restrict__ Oa, const float* __restrict__ Ob,
                const float* __restrict__ Xa, const float* __restrict__ Xb,
                const float* __restrict__ Pgrr, const float* __restrict__ Pgri,
                const float* __restrict__ Pgii, const float* __restrict__ Pbr,
                const float* __restrict__ Pbi,
                float* __restrict__ X2a, float* __restrict__ X2b)
{
    __shared__ float ra[32][132];
    __shared__ float rb[32][132];
    const int tid = threadIdx.x;
    const int m0 = blockIdx.x * 32;
    const int bh = blockIdx.y;
    const int b = bh >> 1, h = bh & 1;
    {
        const float* Xpa = Xa + ((size_t)b*Cc + h*Dd)*Mt + m0;
        const float* Xpb = Xb + ((size_t)b*Cc + h*Dd)*Mt + m0;
        for (int idx = tid; idx < 1024; idx += 256) {
            const int c = idx >> 3, jq = idx & 7;
            float4 a4 = *(const float4*)(Xpa + (size_t)c*Mt + jq*4);
            float4 b4 = *(const float4*)(Xpb + (size_t)c*Mt + jq*4);
            ra[jq*4+0][c] = a4.x; ra[jq*4+1][c] = a4.y;
            ra[jq*4+2][c] = a4.z; ra[jq*4+3][c] = a4.w;
            rb[jq*4+0][c] = b4.x; rb[jq*4+1][c] = b4.y;
            rb[jq*4+2][c] = b4.z; rb[jq*4+3][c] = b4.w;
        }
    }
    __syncthreads();
    const int wave = tid >> 6, lane = tid & 63;
    const float grr0 = Pgrr[lane], grr1 = Pgrr[lane+64];
    const float gri0 = Pgri[lane], gri1 = Pgri[lane+64];
    const float gii0 = Pgii[lane], gii1 = Pgii[lane+64];
    const float br0  = Pbr[lane],  br1  = Pbr[lane+64];
    const float bi0  = Pbi[lane],  bi1  = Pbi[lane+64];
    for (int r = wave; r < 32; r += 4) {
        const size_t rowoff = ((size_t)bh*Mt + m0 + r)*Dd;
        float a0 = Oa[rowoff + lane], a1 = Oa[rowoff + lane + 64];
        float c0 = Ob[rowoff + lane], c1 = Ob[rowoff + lane + 64];
        const float ma = wsum64(a0 + a1) * (1.f/128.f);
        const float mb = wsum64(c0 + c1) * (1.f/128.f);
        a0 -= ma; a1 -= ma; c0 -= mb; c1 -= mb;
        const float vrr = wsum64(a0*a0 + a1*a1) * (1.f/128.f) + 1e-20f;
        const float vii = wsum64(c0*c0 + c1*c1) * (1.f/128.f) + 1e-20f;
        const float vri = wsum64(a0*c0 + a1*c1) * (1.f/128.f);
        const float s = sqrtf(fmaxf(vrr*vii - vri*vri, 0.f));
        const float t = sqrtf(vrr + vii + 2.f*s);
        const float inv = 1.f / (s*t);
        const float wrr = (vii + s)*inv, wii = (vrr + s)*inv, wri = -vri*inv;
        const float na0 = wrr*a0 + wri*c0, nb0 = wri*a0 + wii*c0;
        const float na1 = wrr*a1 + wri*c1, nb1 = wri*a1 + wii*c1;
        X2a[rowoff + lane]      = ra[r][lane]    + grr0*na0 + gri0*nb0 + br0;
        X2a[rowoff + lane + 64] = ra[r][lane+64] + grr1*na1 + gri1*nb1 + br1;
        X2b[rowoff + lane]      = rb[r][lane]    + gri0*na0 + gii0*nb0 + bi0;
        X2b[rowoff + lane + 64] = rb[r][lane+64] + gri1*na1 + gii1*nb1 + bi1;
    }
}

// ---------------------------------------------------------------------------
// MFMA complex linear v2 (hi/lo bf16 split) with LDS-staged weights:
//   Ha = A@Wr^T - B@Wi^T + br ; Hb = A@Wi^T + B@Wr^T + bi ; optional relu.
// W consumed in 16KB chunks (16 output rows: 8KB Wr + 8KB Wi), double-
// buffered.  Activation fragments precomputed in registers (all loads
// precede the epilogue stores -> in-place safe).  Per-accumulator MFMA
// order unchanged (cs ascending) -> bit-identical results.
// grid (BHt*Mt/64), block 256
// ---------------------------------------------------------------------------
__global__ __launch_bounds__(256)
void k_ffn_mfma(const float* __restrict__ A, const float* __restrict__ Bm,
                const uint* __restrict__ Wrp, const uint* __restrict__ Wip,
                const float* __restrict__ br, const float* __restrict__ bi,
                float* __restrict__ Ha, float* __restrict__ Hb, int relu)
{
    __shared__ __align__(16) char wbuf[2][16384];   // 2 x (8KB Wr + 8KB Wi)
    const int tid = threadIdx.x;
    const size_t r0 = (size_t)blockIdx.x * 64;
    const int w = tid >> 6, l = tid & 63;
    const int l15 = l & 15, g = l >> 4;
    const size_t row = r0 + (size_t)w*16 + l15;

    // ---- activation fragments (precomputed once)
    bf16x8 ah[4], al[4], bh_[4], bl_[4], nh[4], nl[4];
    {
        const float* ap = A  + row*Dd + g*8;
        const float* bp = Bm + row*Dd + g*8;
        #pragma unroll
        for (int cs = 0; cs < 4; cs++) {
            const float4 a0 = *(const float4*)(ap + cs*32);
            const float4 a1 = *(const float4*)(ap + cs*32 + 4);
            const float4 b0 = *(const float4*)(bp + cs*32);
            const float4 b1 = *(const float4*)(bp + cs*32 + 4);
            const float av[8] = {a0.x,a0.y,a0.z,a0.w,a1.x,a1.y,a1.z,a1.w};
            const float bv[8] = {b0.x,b0.y,b0.z,b0.w,b1.x,b1.y,b1.z,b1.w};
            #pragma unroll
            for (int j = 0; j < 8; j++) {
                ushort h1, l1; split2(av[j], h1, l1);
                ah[cs][j] = (short)h1; al[cs][j] = (short)l1;
                split2(bv[j], h1, l1);
                bh_[cs][j] = (short)h1; bl_[cs][j] = (short)l1;
                nh[cs][j] = (short)(h1 ^ 0x8000);
                nl[cs][j] = (short)(l1 ^ 0x8000);
            }
        }
    }

    f32x4 accr[8], acci[8];
    #pragma unroll
    for (int nt = 0; nt < 8; nt++) {
        accr[nt] = (f32x4){0.f, 0.f, 0.f, 0.f};
        acci[nt] = (f32x4){0.f, 0.f, 0.f, 0.f};
    }

    auto stage = [&](int p, const uint* wr_, const uint* wi_) {
        char* dst = wbuf[p];
        #pragma unroll
        for (int r = 0; r < 2; r++) {
            const int byte = r*4096 + tid*16;
            const int swz = ((byte >> 9) & 7) << 4;
            *(uint4*)(dst + (byte ^ swz)) =
                *(const uint4*)((const char*)wr_ + byte);
            *(uint4*)(dst + 8192 + (byte ^ swz)) =
                *(const uint4*)((const char*)wi_ + byte);
        }
    };

    const int sw = (l15 & 7) << 4;
    stage(0, Wrp, Wip);
    __syncthreads();
    #pragma unroll
    for (int nt = 0; nt < 8; nt++) {
        if (nt < 7) stage((nt + 1) & 1, Wrp + (nt + 1)*2048, Wip + (nt + 1)*2048);
        const char* bufc = wbuf[nt & 1];
        #pragma unroll
        for (int cs = 0; cs < 4; cs++) {
            const int a0 = (l15 << 9) + cs*128 + g*32;
            const uint4 r0v = *(const uint4*)(bufc + (a0 ^ sw));
            const uint4 r1v = *(const uint4*)(bufc + ((a0 + 16) ^ sw));
            const uint4 i0v = *(const uint4*)(bufc + 8192 + (a0 ^ sw));
            const uint4 i1v = *(const uint4*)(bufc + 8192 + ((a0 + 16) ^ sw));
            bf16x8 wrh, wrl, wih, wil;
            unpack8(r0v, r1v, wrh, wrl);
            unpack8(i0v, i1v, wih, wil);
            accr[nt] = __builtin_amdgcn_mfma_f32_16x16x32_bf16(wrh, ah[cs],  accr[nt], 0, 0, 0);
            accr[nt] = __builtin_amdgcn_mfma_f32_16x16x32_bf16(wrh, al[cs],  accr[nt], 0, 0, 0);
            accr[nt] = __builtin_amdgcn_mfma_f32_16x16x32_bf16(wrl, ah[cs],  accr[nt], 0, 0, 0);
            accr[nt] = __builtin_amdgcn_mfma_f32_16x16x32_bf16(wih, nh[cs],  accr[nt], 0, 0, 0);
            accr[nt] = __builtin_amdgcn_mfma_f32_16x16x32_bf16(wih, nl[cs],  accr[nt], 0, 0, 0);
            accr[nt] = __builtin_amdgcn_mfma_f32_16x16x32_bf16(wil, nh[cs],  accr[nt], 0, 0, 0);
            acci[nt] = __builtin_amdgcn_mfma_f32_16x16x32_bf16(wih, ah[cs],  acci[nt], 0, 0, 0);
            acci[nt] = __builtin_amdgcn_mfma_f32_16x16x32_bf16(wih, al[cs],  acci[nt], 0, 0, 0);
            acci[nt] = __builtin_amdgcn_mfma_f32_16x16x32_bf16(wil, ah[cs],  acci[nt], 0, 0, 0);
            acci[nt] = __builtin_amdgcn_mfma_f32_16x16x32_bf16(wrh, bh_[cs], acci[nt], 0, 0, 0);
            acci[nt] = __builtin_amdgcn_mfma_f32_16x16x32_bf16(wrh, bl_[cs], acci[nt], 0, 0, 0);
            acci[nt] = __builtin_amdgcn_mfma_f32_16x16x32_bf16(wrl, bh_[cs], acci[nt], 0, 0, 0);
        }
        __syncthreads();
    }

    #pragma unroll
    for (int nt = 0; nt < 8; nt++) {
        const int n0 = nt*16 + g*4;
        const float4 vbr = *(const float4*)(br + n0);
        const float4 vbi = *(const float4*)(bi + n0);
        const float brv[4] = {vbr.x, vbr.y, vbr.z, vbr.w};
        const float biv[4] = {vbi.x, vbi.y, vbi.z, vbi.w};
        float4 orv, oiv;
        float* po = &orv.x; float* pj = &oiv.x;
        #pragma unroll
        for (int r = 0; r < 4; r++) {
            float hr = accr[nt][r] + brv[r];
            float hi = acci[nt][r] + biv[r];
            if (relu) { hr = fmaxf(hr, 0.f); hi = fmaxf(hi, 0.f); }
            po[r] = hr; pj[r] = hi;
        }
        *(float4*)(Ha + row*Dd + n0) = orv;
        *(float4*)(Hb + row*Dd + n0) = oiv;
    }
}

// ---------------------------------------------------------------------------
// Complex whitening LN (FFN branch) + residual (token-major) + transpose out
// to (B,C,M). grid (Mt/32, BHt), block 256
// ---------------------------------------------------------------------------
__global__ __launch_bounds__(256)
void k_cln_ffn(const float* __restrict__ Ha2, const float* __restrict__ Hb2,
               const float* __restrict__ X2a, const float* __restrict__ X2b,
               const float* __restrict__ Pgrr, const float* __restrict__ Pgri,
               const float* __restrict__ Pgii, const float* __restrict__ Pbr,
               const float* __restrict__ Pbi,
               float* __restrict__ OutA, float* __restrict__ OutB)
{
    __shared__ float oA[128][36];
    __shared__ float oB[128][36];
    const int tid = threadIdx.x;
    const int m0 = blockIdx.x * 32;
    const int bh = blockIdx.y;
    const int b = bh >> 1, h = bh & 1;
    const int wave = tid >> 6, lane = tid & 63;
    const float grr0 = Pgrr[lane], grr1 = Pgrr[lane+64];
    const float gri0 = Pgri[lane], gri1 = Pgri[lane+64];
    const float gii0 = Pgii[lane], gii1 = Pgii[lane+64];
    const float br0  = Pbr[lane],  br1  = Pbr[lane+64];
    const float bi0  = Pbi[lane],  bi1  = Pbi[lane+64];
    for (int r = wave; r < 32; r += 4) {
        const size_t rowoff = ((size_t)bh*Mt + m0 + r)*Dd;
        float a0 = Ha2[rowoff + lane], a1 = Ha2[rowoff + lane + 64];
        float c0 = Hb2[rowoff + lane], c1 = Hb2[rowoff + lane + 64];
        const float ma = wsum64(a0 + a1) * (1.f/128.f);
        const float mb = wsum64(c0 + c1) * (1.f/128.f);
        a0 -= ma; a1 -= ma; c0 -= mb; c1 -= mb;
        const float vrr = wsum64(a0*a0 + a1*a1) * (1.f/128.f) + 1e-20f;
        const float vii = wsum64(c0*c0 + c1*c1) * (1.f/128.f) + 1e-20f;
        const float vri = wsum64(a0*c0 + a1*c1) * (1.f/128.f);
        const float s = sqrtf(fmaxf(vrr*vii - vri*vri, 0.f));
        const float t = sqrtf(vrr + vii + 2.f*s);
        const float inv = 1.f / (s*t);
        const float wrr = (vii + s)*inv, wii = (vrr + s)*inv, wri = -vri*inv;
        const float na0 = wrr*a0 + wri*c0, nb0 = wri*a0 + wii*c0;
        const float na1 = wrr*a1 + wri*c1, nb1 = wri*a1 + wii*c1;
        oA[lane][r]    = X2a[rowoff + lane]      + grr0*na0 + gri0*nb0 + br0;
        oA[lane+64][r] = X2a[rowoff + lane + 64] + grr1*na1 + gri1*nb1 + br1;
        oB[lane][r]    = X2b[rowoff + lane]      + gri0*na0 + gii0*nb0 + bi0;
        oB[lane+64][r] = X2b[rowoff + lane + 64] + gri1*na1 + gii1*nb1 + bi1;
    }
    __syncthreads();
    const size_t obase = ((size_t)b*Cc + h*Dd)*Mt + m0;
    for (int idx = tid; idx < 1024; idx += 256) {
        const int c = idx >> 3, jq = idx & 7;
        *(float4*)(OutA + obase + (size_t)c*Mt + jq*4) = *(const float4*)&oA[c][jq*4];
        *(float4*)(OutB + obase + (size_t)c*Mt + jq*4) = *(const float4*)&oB[c][jq*4];
    }
}

// ---------------------------------------------------------------------------
extern "C" void kernel_launch(void* const* d_in, const int* in_sizes, int n_in,
                              void* d_out, int out_size, void* d_ws, size_t ws_size,
                              hipStream_t stream)
{
    const float* xA0 = (const float*)d_in[0];
    const float* xB0 = (const float*)d_in[1];
    const float* wq  = (const float*)d_in[2];
    const float* bq  = (const float*)d_in[3];
    const float* wk  = (const float*)d_in[4];
    const float* bk  = (const float*)d_in[5];
    const float* wv  = (const float*)d_in[6];
    const float* bv  = (const float*)d_in[7];
    const float* dww = (const float*)d_in[8];
    const float* dwb = (const float*)d_in[9];
    const float* lng = (const float*)d_in[10];
    const float* lnb = (const float*)d_in[11];
    const float* pw  = (const float*)d_in[12];
    const float* f1wr = (const float*)d_in[13];
    const float* f1wi = (const float*)d_in[14];
    const float* f1br = (const float*)d_in[15];
    const float* f1bi = (const float*)d_in[16];
    const float* f2wr = (const float*)d_in[17];
    const float* f2wi = (const float*)d_in[18];
    const float* f2br = (const float*)d_in[19];
    const float* f2bi = (const float*)d_in[20];
    const float* lgrr = (const float*)d_in[21];
    const float* lgri = (const float*)d_in[22];
    const float* lgii = (const float*)d_in[23];
    const float* lbr  = (const float*)d_in[24];
    const float* lbi  = (const float*)d_in[25];
    const float* rpe  = (const float*)d_in[26];

    float* ws = (float*)d_ws;
    const size_t NB = (size_t)Bz * Cc * Mt;     // 16777216 floats (64 MB)
    const size_t SC = (size_t)Bz * Cc * NSs;    // 262144 floats (1 MB)
    float* Pa  = ws;        float* Pb  = Pa  + NB;
    float* Ra  = Pb  + NB;  float* Rb  = Ra  + NB;
    float* Ya  = Rb  + NB;  float* Yb  = Ya  + SC;
    float* XsA = Yb  + SC;  float* XsB = XsA + SC;
    float* Kab = XsB + SC;  float* Kbb = Kab + SC;
    float* Vab = Kbb + SC;  float* Vbb = Vab + SC;
    float* Sp0 = Vbb + SC;  float* Sp1 = Sp0 + SC;
    float* PosA = Sp1 + SC; float* PosB = PosA + (size_t)Bz*NSs*2;
    float* Wpf  = PosB + (size_t)Bz*NSs*2;       // ffn 4*16384 + wq 65536 u32

    uint*   Qs   = (uint*)Ra;        // also used as Xt (input split) early on
    ushort* KtpH = (ushort*)Sp0;     // K hi plane (1 MB)
    ushort* KtpL = (ushort*)Sp1;     // K lo plane (1 MB)
    ushort* VsH  = (ushort*)Ya;      // V hi plane (1 MB)
    ushort* VsL  = (ushort*)Yb;      // V lo plane (1 MB)
    uint*   Wp   = (uint*)Wpf;                   // ffn weights (4 x 128x128)
    uint*   Wqp  = Wp + (size_t)4*Dd*Dd;         // wq (256x256)

    float* outAf = (float*)d_out;
    float* outBf = outAf + NB;

    for (int l = 0; l < LAYERS; l++) {
        const float* pwq = wq + (size_t)l*Cc*Cc;
        const float* pbq = bq + (size_t)l*Cc;
        const float* pwk = wk + (size_t)l*Cc*Cc;
        const float* pbk = bk + (size_t)l*Cc;
        const float* pwv = wv + (size_t)l*Cc*Cc;
        const float* pbv = bv + (size_t)l*Cc;
        const float* pdww = dww + (size_t)l*Cc*81;
        const float* pdwb = dwb + (size_t)l*Cc;
        const float* plng = lng + (size_t)l*Cc;
        const float* plnb = lnb + (size_t)l*Cc;
        const float* ppw  = pw  + (size_t)l*2*Cc;
        const float* p1wr = f1wr + (size_t)l*Dd*Dd;
        const float* p1wi = f1wi + (size_t)l*Dd*Dd;
        const float* p1br = f1br + (size_t)l*Dd;
        const float* p1bi = f1bi + (size_t)l*Dd;
        const float* p2wr = f2wr + (size_t)l*Dd*Dd;
        const float* p2wi = f2wi + (size_t)l*Dd*Dd;
        const float* p2br = f2br + (size_t)l*Dd;
        const float* p2bi = f2bi + (size_t)l*Dd;
        const float* g0rr = lgrr + (size_t)(l*2+0)*Dd;
        const float* g0ri = lgri + (size_t)(l*2+0)*Dd;
        const float* g0ii = lgii + (size_t)(l*2+0)*Dd;
        const float* g0br = lbr  + (size_t)(l*2+0)*Dd;
        const float* g0bi = lbi  + (size_t)(l*2+0)*Dd;
        const float* g1rr = lgrr + (size_t)(l*2+1)*Dd;
        const float* g1ri = lgri + (size_t)(l*2+1)*Dd;
        const float* g1ii = lgii + (size_t)(l*2+1)*Dd;
        const float* g1br = lbr  + (size_t)(l*2+1)*Dd;
        const float* g1bi = lbi  + (size_t)(l*2+1)*Dd;
        const float* prpe = rpe + (size_t)l*NHh*RPH*RPW;

        const float* inA = l ? outAf : xA0;
        const float* inB = l ? outBf : xB0;

        // weight packing for this layer (independent of everything else)
        dim3 gW(64, 4);
        k_wsplit4<<<gW, 256, 0, stream>>>(p1wr, p1wi, p2wr, p2wi, Wp);
        k_wsplit1<<<256, 256, 0, stream>>>(pwq, Wqp);

        // input split (token-major packed) -> Xt in Ra/Rb region
        dim3 gQs(Mt/64, BHt);
        k_qsplit<<<gQs, 256, 0, stream>>>(inA, inB, Qs);   // Qs == Xt here

        // Q projection via MFMA (LDS-staged W): Xt x Wq -> Pa/Pb ([c][m] f32)
        dim3 gPQ(Mt/64, Bz);
        k_projq_mfma<<<gPQ, 256, 0, stream>>>(Qs, Wqp, pbq, Pa, 0);
        k_projq_mfma<<<gPQ, 256, 0, stream>>>(Qs, Wqp, pbq, Pb, 1);

        dim3 gD(Cc, Bz);
        k_dwconv<<<gD, 256, 0, stream>>>(Pa, pdww, pdwb, Ya);
        k_dwconv<<<gD, 256, 0, stream>>>(Pb, pdww, pdwb, Yb);

        dim3 gL(NSs, Bz);
        k_lnpw<<<gL, 256, 0, stream>>>(Ya, plng, plnb, ppw, PosA);
        k_lnpw<<<gL, 256, 0, stream>>>(Yb, plng, plnb, ppw, PosB);

        dim3 gS(Cc, Bz);
        k_gsample<<<gS, 256, 0, stream>>>(inA, PosA, XsA);
        k_gsample<<<gS, 256, 0, stream>>>(inB, PosB, XsB);

        dim3 gKV(NSs/64, Cc/64, Bz);
        k_proj<<<gKV, 256, 0, stream>>>(XsA, pwk, pbk, Kab, NSs);
        k_proj<<<gKV, 256, 0, stream>>>(XsB, pwk, pbk, Kbb, NSs);
        k_proj<<<gKV, 256, 0, stream>>>(XsA, pwv, pbv, Vab, NSs);
        k_proj<<<gKV, 256, 0, stream>>>(XsB, pwv, pbv, Vbb, NSs);

        // plane bf16 pre-splits (Ya/Yb dead after k_lnpw)
        dim3 gKs(NSs/64, BHt);
        k_ksplit<<<gKs, 256, 0, stream>>>(Kab, Kbb, KtpH, KtpL);
        k_vsplit<<<1024, 256, 0, stream>>>(Vab, Vbb, VsH, VsL);
        // Q split (overwrites Xt -- dead after projq)
        k_qsplit<<<gQs, 256, 0, stream>>>(Pa, Pb, Qs);

        // attn: Qs(R) -> O(P).  Qs dead afterwards.
        dim3 gA(Mt/64, BHt);
        k_attn_mfma<<<gA, 256, 0, stream>>>(Qs, KtpH, KtpL, VsH, VsL,
                                            PosA, prpe, Pa, Pb);

        // cln_attn: O(P) + X(in) -> X2(R).
        dim3 gC(Mt/32, BHt);
        k_cln_attn<<<gC, 256, 0, stream>>>(Pa, Pb, inA, inB,
                                           g0rr, g0ri, g0ii, g0br, g0bi, Ra, Rb);

        // fc1: X2(R) -> H1(P); fc2: H1(P) -> H2(P) in-place.  (MFMA hi/lo)
        dim3 gF((unsigned)((size_t)BHt*Mt/64));
        k_ffn_mfma<<<gF, 256, 0, stream>>>(Ra, Rb, Wp, Wp + (size_t)Dd*Dd,
                                           p1br, p1bi, Pa, Pb, 1);
        k_ffn_mfma<<<gF, 256, 0, stream>>>(Pa, Pb, Wp + (size_t)2*Dd*Dd,
                                           Wp + (size_t)3*Dd*Dd,
                                           p2br, p2bi, Pa, Pb, 0);

        // cln_ffn: H2(P) + X2(R) -> layer output
        k_cln_ffn<<<gC, 256, 0, stream>>>(Pa, Pb, Ra, Rb,
                                          g1rr, g1ri, g1ii, g1br, g1bi, outAf, outBf);
    }
    (void)in_sizes; (void)n_in; (void)out_size; (void)ws_size;
}